// Round 5
// baseline (763.150 us; speedup 1.0000x reference)
//
#include <hip/hip_runtime.h>
#include <cstdint>
#include <cstddef>

typedef short bf16x8 __attribute__((ext_vector_type(8)));
typedef float f32x4 __attribute__((ext_vector_type(4)));

#define B_ 2
#define T_ 2048
#define DIN 2048
#define H_ 32
#define HD_ 64
#define KV_ 8

__device__ __forceinline__ unsigned short f2b(float f) {
  unsigned int u = __float_as_uint(f);
  u += 0x7fffu + ((u >> 16) & 1u);
  return (unsigned short)(u >> 16);
}

__device__ __forceinline__ float b2f(unsigned short b) {
  return __uint_as_float(((unsigned int)b) << 16);
}

__device__ __forceinline__ void gload_lds16(const void* g, void* l) {
  __builtin_amdgcn_global_load_lds(
      (const unsigned int __attribute__((address_space(1)))*)g,
      (unsigned int __attribute__((address_space(3)))*)l, 16, 0, 0);
}

__global__ __launch_bounds__(256) void cvt_bf16(const float* __restrict__ in,
                                                unsigned short* __restrict__ out,
                                                int n4) {
  int i = blockIdx.x * 256 + threadIdx.x;
  if (i >= n4) return;
  float4 v = ((const float4*)in)[i];
  uint2 o;
  o.x = (unsigned)f2b(v.x) | ((unsigned)f2b(v.y) << 16);
  o.y = (unsigned)f2b(v.z) | ((unsigned)f2b(v.w) << 16);
  ((uint2*)out)[i] = o;
}

// C[M][N] = A[M][K] * Bw[N][K]^T (+bias). bf16 inputs; f32 or bf16 out.
__global__ __launch_bounds__(256) void gemm_bt(const unsigned short* __restrict__ A,
                                               const unsigned short* __restrict__ Bw,
                                               const float* __restrict__ bias,
                                               void* __restrict__ Cout,
                                               int M, int N, int K, int out_bf16) {
  __shared__ short As[128 * 64];
  __shared__ short Bs[128 * 64];
  const int tid = threadIdx.x;
  const int lane = tid & 63;
  const int wid = tid >> 6;
  const int wr = (wid >> 1) * 64;
  const int wc = (wid & 1) * 64;
  const int bm = blockIdx.y * 128;
  const int bn = blockIdx.x * 128;
  const int lr = lane & 15;
  const int lk = (lane >> 4) * 8;
  f32x4 acc[4][4] = {};

  for (int kt = 0; kt < K; kt += 64) {
    __syncthreads();
#pragma unroll
    for (int it = 0; it < 4; ++it) {
      int c = it * 256 + tid;
      int r = c >> 3;
      int c8 = (c & 7) * 8;
      gload_lds16(A + (size_t)(bm + r) * K + kt + c8, &As[c * 8]);
      gload_lds16(Bw + (size_t)(bn + r) * K + kt + c8, &Bs[c * 8]);
    }
    __syncthreads();
#pragma unroll
    for (int kk = 0; kk < 2; ++kk) {
      bf16x8 af[4], bfr[4];
#pragma unroll
      for (int m = 0; m < 4; ++m)
        af[m] = *(const bf16x8*)&As[(wr + m * 16 + lr) * 64 + kk * 32 + lk];
#pragma unroll
      for (int n = 0; n < 4; ++n)
        bfr[n] = *(const bf16x8*)&Bs[(wc + n * 16 + lr) * 64 + kk * 32 + lk];
#pragma unroll
      for (int m = 0; m < 4; ++m)
#pragma unroll
        for (int n = 0; n < 4; ++n)
          acc[m][n] = __builtin_amdgcn_mfma_f32_16x16x32_bf16(af[m], bfr[n], acc[m][n], 0, 0, 0);
    }
  }
  const int r0 = bm + wr + (lane >> 4) * 4;
  const int c0 = bn + wc + lr;
#pragma unroll
  for (int m = 0; m < 4; ++m)
#pragma unroll
    for (int n = 0; n < 4; ++n) {
      int col = c0 + n * 16;
      float bb = bias ? bias[col] : 0.0f;
#pragma unroll
      for (int r = 0; r < 4; ++r) {
        float val = acc[m][n][r] + bb;
        size_t idx = (size_t)(r0 + m * 16 + r) * N + col;
        if (out_bf16)
          ((unsigned short*)Cout)[idx] = f2b(val);
        else
          ((float*)Cout)[idx] = val;
      }
    }
}

// bias + RoPE + scatter into attention layouts; K/V also to f32 outputs.
__global__ __launch_bounds__(256) void rope_scatter(
    const unsigned short* __restrict__ cqkv, const float* __restrict__ bq,
    const float* __restrict__ bk, const float* __restrict__ bv,
    const float* __restrict__ cosp, const float* __restrict__ sinp,
    unsigned short* __restrict__ qbuf, unsigned short* __restrict__ kbuf,
    unsigned short* __restrict__ vbuf, float* __restrict__ kout,
    float* __restrict__ vout) {
  const int bt = blockIdx.x;
  const int b = bt >> 11;
  const int t = bt & 2047;
  const int tid = threadIdx.x;
  const unsigned short* row = cqkv + (size_t)bt * 3072;

  // Q: 1024 rope pairs, scaled by 1/8 (exact in bf16)
  for (int p = tid; p < 1024; p += 256) {
    int h = p >> 5, i = p & 31;
    float c = cosp[t * 32 + i], s = sinp[t * 32 + i];
    float q0 = b2f(row[2 * p]) + bq[2 * p];
    float q1 = b2f(row[2 * p + 1]) + bq[2 * p + 1];
    float qe = (q0 * c - q1 * s) * 0.125f;
    float qo = (q0 * s + q1 * c) * 0.125f;
    size_t base = ((size_t)(b * H_ + h) * T_ + t) * HD_ + 2 * i;
    qbuf[base] = f2b(qe);
    qbuf[base + 1] = f2b(qo);
  }
  // K: 256 rope pairs
  {
    int p = tid;
    if (p < 256) {
      int kvh = p >> 5, i = p & 31;
      float c = cosp[t * 32 + i], s = sinp[t * 32 + i];
      float k0 = b2f(row[2048 + 2 * p]) + bk[2 * p];
      float k1 = b2f(row[2048 + 2 * p + 1]) + bk[2 * p + 1];
      float ke = k0 * c - k1 * s;
      float ko = k0 * s + k1 * c;
      size_t base = ((size_t)(b * KV_ + kvh) * T_ + t) * HD_ + 2 * i;
      kout[base] = ke;
      kout[base + 1] = ko;
      kbuf[base] = f2b(ke);
      kbuf[base + 1] = f2b(ko);
    }
  }
  // V: 512 elems
  for (int j = tid; j < 512; j += 256) {
    int kvh = j >> 6, d = j & 63;
    float v = b2f(row[2560 + j]) + bv[j];
    size_t base = ((size_t)(b * KV_ + kvh) * T_ + t) * HD_ + d;
    vout[base] = v;
    vbuf[base] = f2b(v);
  }
}

// Tiled transpose: vbuf[bk][t][d] -> vtb[bk][d][t].  grid(T/64, B*KV), 256 thr.
__global__ __launch_bounds__(256) void transpose_v(const unsigned short* __restrict__ vbuf,
                                                   unsigned short* __restrict__ vtb) {
  __shared__ unsigned short tile[64][72];
  const int tid = threadIdx.x;
  const int bk = blockIdx.y;
  const int t0 = blockIdx.x * 64;
  const unsigned short* src = vbuf + ((size_t)bk * T_ + t0) * HD_;
#pragma unroll
  for (int it = 0; it < 2; ++it) {
    int c = it * 256 + tid;
    int r = c >> 3;            // local t
    int c8 = (c & 7) * 8;      // d start
    *(bf16x8*)&tile[r][c8] = *(const bf16x8*)(src + (size_t)r * HD_ + c8);
  }
  __syncthreads();
  unsigned short* dst = vtb + (size_t)bk * HD_ * T_;
#pragma unroll
  for (int it = 0; it < 2; ++it) {
    int o = it * 256 + tid;
    int d = o >> 3;            // output row
    int t8 = (o & 7) * 8;      // t start
    bf16x8 v;
#pragma unroll
    for (int j = 0; j < 8; ++j) v[j] = (short)tile[t8 + j][d];
    *(bf16x8*)(dst + (size_t)d * T_ + t0 + t8) = v;
  }
}

// Causal GQA flash attention — barrier-free. grid(qtile, H, B), 4 waves x 16 q-rows.
// K read from global (row-major), V read from global pre-transposed vtb[d][t].
__global__ __launch_bounds__(256) void attn(const unsigned short* __restrict__ Q,
                                            const unsigned short* __restrict__ Kb,
                                            const unsigned short* __restrict__ Vtb,
                                            unsigned short* __restrict__ ctx) {
  __shared__ short Pw[4][16 * 72];   // per-wave P tile [qrow][kv], stride 72 breaks conflicts
  const int qtile = (int)gridDim.x - 1 - blockIdx.x;  // heavy tiles first
  const int h = blockIdx.y, bz = blockIdx.z;
  const int kvh = h >> 2;
  const int tid = threadIdx.x, lane = tid & 63, w = tid >> 6;
  const int lr = lane & 15;
  const int lk = (lane >> 4) * 8;
  const float NEGINF = -__builtin_inff();

  const unsigned short* qbase =
      Q + ((size_t)(bz * H_ + h) * T_ + qtile * 64 + w * 16) * HD_;
  bf16x8 qf[2];
  qf[0] = *(const bf16x8*)(qbase + (size_t)lr * HD_ + lk);
  qf[1] = *(const bf16x8*)(qbase + (size_t)lr * HD_ + 32 + lk);

  float mrun[4] = {NEGINF, NEGINF, NEGINF, NEGINF};
  float lrun[4] = {0.f, 0.f, 0.f, 0.f};
  f32x4 acc[4] = {};

  const unsigned short* kb = Kb + (size_t)(bz * KV_ + kvh) * T_ * HD_;
  const unsigned short* vt = Vtb + (size_t)(bz * KV_ + kvh) * HD_ * T_;  // [d][t]

  for (int kt = 0; kt <= qtile; ++kt) {
    // scores: S[16 q][64 kv] per wave  (K direct from global)
    f32x4 s[4];
#pragma unroll
    for (int cb = 0; cb < 4; ++cb) {
      s[cb] = (f32x4){0.f, 0.f, 0.f, 0.f};
#pragma unroll
      for (int kk = 0; kk < 2; ++kk) {
        bf16x8 kf = *(const bf16x8*)(kb + (size_t)(kt * 64 + cb * 16 + lr) * HD_ +
                                     kk * 32 + lk);
        s[cb] = __builtin_amdgcn_mfma_f32_16x16x32_bf16(qf[kk], kf, s[cb], 0, 0, 0);
      }
    }
    if (kt == qtile) {  // causal mask on diagonal tile
#pragma unroll
      for (int cb = 0; cb < 4; ++cb) {
        int col = kt * 64 + cb * 16 + lr;
#pragma unroll
        for (int r = 0; r < 4; ++r) {
          int rowq = qtile * 64 + w * 16 + (lane >> 4) * 4 + r;
          if (col > rowq) s[cb][r] = NEGINF;
        }
      }
    }
    // online softmax (rows live in 16-lane groups)
#pragma unroll
    for (int r = 0; r < 4; ++r) {
      float v = fmaxf(fmaxf(s[0][r], s[1][r]), fmaxf(s[2][r], s[3][r]));
      v = fmaxf(v, __shfl_xor(v, 1));
      v = fmaxf(v, __shfl_xor(v, 2));
      v = fmaxf(v, __shfl_xor(v, 4));
      v = fmaxf(v, __shfl_xor(v, 8));
      float mnew = fmaxf(mrun[r], v);
      float sc = __expf(mrun[r] - mnew);
      mrun[r] = mnew;
      float ps = 0.f;
#pragma unroll
      for (int cb = 0; cb < 4; ++cb) {
        float p = __expf(s[cb][r] - mnew);
        s[cb][r] = p;
        ps += p;
      }
      ps += __shfl_xor(ps, 1);
      ps += __shfl_xor(ps, 2);
      ps += __shfl_xor(ps, 4);
      ps += __shfl_xor(ps, 8);
      lrun[r] = lrun[r] * sc + ps;
#pragma unroll
      for (int cb = 0; cb < 4; ++cb) {
        acc[cb][r] *= sc;
        Pw[w][((lane >> 4) * 4 + r) * 72 + cb * 16 + lr] = (short)f2b(s[cb][r]);
      }
    }
    // PV: ctx[16 q][64 hd] += P[16][64] @ V[64][64]  (V^T direct from global)
    bf16x8 pa[2];
    pa[0] = *(const bf16x8*)&Pw[w][lr * 72 + lk];
    pa[1] = *(const bf16x8*)&Pw[w][lr * 72 + 32 + lk];
#pragma unroll
    for (int cb = 0; cb < 4; ++cb) {
      bf16x8 vf0 = *(const bf16x8*)(vt + (size_t)(cb * 16 + lr) * T_ + kt * 64 + lk);
      bf16x8 vf1 = *(const bf16x8*)(vt + (size_t)(cb * 16 + lr) * T_ + kt * 64 + 32 + lk);
      acc[cb] = __builtin_amdgcn_mfma_f32_16x16x32_bf16(pa[0], vf0, acc[cb], 0, 0, 0);
      acc[cb] = __builtin_amdgcn_mfma_f32_16x16x32_bf16(pa[1], vf1, acc[cb], 0, 0, 0);
    }
  }
  // epilogue: ctx[b][t][h*64+d] bf16
#pragma unroll
  for (int cb = 0; cb < 4; ++cb)
#pragma unroll
    for (int r = 0; r < 4; ++r) {
      int rowq = qtile * 64 + w * 16 + (lane >> 4) * 4 + r;
      ctx[((size_t)bz * T_ + rowq) * DIN + h * HD_ + cb * 16 + lr] =
          f2b(acc[cb][r] / lrun[r]);
    }
}

extern "C" void kernel_launch(void* const* d_in, const int* in_sizes, int n_in,
                              void* d_out, int out_size, void* d_ws, size_t ws_size,
                              hipStream_t stream) {
  const float* x = (const float*)d_in[0];
  const float* cosp = (const float*)d_in[1];
  const float* sinp = (const float*)d_in[2];
  const float* wq = (const float*)d_in[3];
  const float* bq = (const float*)d_in[4];
  const float* wk = (const float*)d_in[5];
  const float* bk = (const float*)d_in[6];
  const float* wv = (const float*)d_in[7];
  const float* bv = (const float*)d_in[8];
  const float* wo = (const float*)d_in[9];
  const float* bo = (const float*)d_in[10];

  float* out = (float*)d_out;
  float* kout = out + (size_t)B_ * T_ * DIN;
  float* vout = kout + (size_t)B_ * KV_ * T_ * HD_;

  // Workspace layout with reuse (peak 60 MB):
  //   region A @ 0MB  (16MB): xb      -> qbuf  (xb dead after gemm1)
  //   region B @ 16MB (12MB): wqkv    -> kbuf+vbuf (wqkv dead after gemm1)
  //   region C @ 28MB ( 8MB): wob     (static)
  //   region D @ 36MB (24MB): cqkv bf16 -> ctxb(36..52) + vtb(52..56) (cqkv dead after rope)
  char* ws = (char*)d_ws;
  unsigned short* xb   = (unsigned short*)(ws + 0);
  unsigned short* wqkv = (unsigned short*)(ws + (size_t)16 * 1024 * 1024);
  unsigned short* wob  = (unsigned short*)(ws + (size_t)28 * 1024 * 1024);
  unsigned short* cqkv = (unsigned short*)(ws + (size_t)36 * 1024 * 1024);

  unsigned short* qbuf = xb;
  unsigned short* kbuf = wqkv;
  unsigned short* vbuf = wqkv + (size_t)2097152;
  unsigned short* ctxb = cqkv;
  unsigned short* vtb  = (unsigned short*)(ws + (size_t)52 * 1024 * 1024);

  // f32 -> bf16 conversions
  cvt_bf16<<<8192, 256, 0, stream>>>(x, xb, 2097152);
  cvt_bf16<<<4096, 256, 0, stream>>>(wq, wqkv, 1048576);
  cvt_bf16<<<1024, 256, 0, stream>>>(wk, wqkv + (size_t)2048 * 2048, 262144);
  cvt_bf16<<<1024, 256, 0, stream>>>(wv, wqkv + (size_t)2048 * 2048 + (size_t)512 * 2048, 262144);
  cvt_bf16<<<4096, 256, 0, stream>>>(wo, wob, 1048576);

  // QKV projection: (4096 x 2048) @ (3072 x 2048)^T -> bf16 cqkv
  gemm_bt<<<dim3(24, 32), 256, 0, stream>>>(xb, wqkv, nullptr, cqkv, 4096, 3072, 2048, 1);

  // bias + RoPE + scatter
  rope_scatter<<<4096, 256, 0, stream>>>(cqkv, bq, bk, bv, cosp, sinp, qbuf, kbuf,
                                         vbuf, kout, vout);

  // V transpose: vbuf[t][d] -> vtb[d][t]
  transpose_v<<<dim3(T_ / 64, B_ * KV_), 256, 0, stream>>>(vbuf, vtb);

  // causal GQA flash attention (barrier-free)
  attn<<<dim3(T_ / 64, H_, B_), 256, 0, stream>>>(qbuf, kbuf, vtb, ctxb);

  // output projection: (4096 x 2048) @ (2048 x 2048)^T + bo -> f32 out
  gemm_bt<<<dim3(16, 32), 256, 0, stream>>>(ctxb, wob, bo, out, 4096, 2048, 2048, 0);
}

// Round 7
// 556.349 us; speedup vs baseline: 1.3717x; 1.3717x over previous
//
#include <hip/hip_runtime.h>
#include <cstdint>
#include <cstddef>

typedef short bf16x8 __attribute__((ext_vector_type(8)));
typedef float f32x4 __attribute__((ext_vector_type(4)));

#define B_ 2
#define T_ 2048
#define DIN 2048
#define H_ 32
#define HD_ 64
#define KV_ 8

__device__ __forceinline__ unsigned short f2b(float f) {
  unsigned int u = __float_as_uint(f);
  u += 0x7fffu + ((u >> 16) & 1u);
  return (unsigned short)(u >> 16);
}

__device__ __forceinline__ float b2f(unsigned short b) {
  return __uint_as_float(((unsigned int)b) << 16);
}

__device__ __forceinline__ void gload_lds16(const void* g, void* l) {
  __builtin_amdgcn_global_load_lds(
      (const unsigned int __attribute__((address_space(1)))*)g,
      (unsigned int __attribute__((address_space(3)))*)l, 16, 0, 0);
}

__global__ __launch_bounds__(256) void cvt_bf16(const float* __restrict__ in,
                                                unsigned short* __restrict__ out,
                                                int n4) {
  int i = blockIdx.x * 256 + threadIdx.x;
  if (i >= n4) return;
  float4 v = ((const float4*)in)[i];
  uint2 o;
  o.x = (unsigned)f2b(v.x) | ((unsigned)f2b(v.y) << 16);
  o.y = (unsigned)f2b(v.z) | ((unsigned)f2b(v.w) << 16);
  ((uint2*)out)[i] = o;
}

// C[M][N] = A[M][K] * Bw[N][K]^T (+bias). bf16 inputs; f32 or bf16 out.
__global__ __launch_bounds__(256) void gemm_bt(const unsigned short* __restrict__ A,
                                               const unsigned short* __restrict__ Bw,
                                               const float* __restrict__ bias,
                                               void* __restrict__ Cout,
                                               int M, int N, int K, int out_bf16) {
  __shared__ short As[128 * 64];
  __shared__ short Bs[128 * 64];
  const int tid = threadIdx.x;
  const int lane = tid & 63;
  const int wid = tid >> 6;
  const int wr = (wid >> 1) * 64;
  const int wc = (wid & 1) * 64;
  const int bm = blockIdx.y * 128;
  const int bn = blockIdx.x * 128;
  const int lr = lane & 15;
  const int lk = (lane >> 4) * 8;
  f32x4 acc[4][4] = {};

  for (int kt = 0; kt < K; kt += 64) {
    __syncthreads();
#pragma unroll
    for (int it = 0; it < 4; ++it) {
      int c = it * 256 + tid;
      int r = c >> 3;
      int c8 = (c & 7) * 8;
      gload_lds16(A + (size_t)(bm + r) * K + kt + c8, &As[c * 8]);
      gload_lds16(Bw + (size_t)(bn + r) * K + kt + c8, &Bs[c * 8]);
    }
    __syncthreads();
#pragma unroll
    for (int kk = 0; kk < 2; ++kk) {
      bf16x8 af[4], bfr[4];
#pragma unroll
      for (int m = 0; m < 4; ++m)
        af[m] = *(const bf16x8*)&As[(wr + m * 16 + lr) * 64 + kk * 32 + lk];
#pragma unroll
      for (int n = 0; n < 4; ++n)
        bfr[n] = *(const bf16x8*)&Bs[(wc + n * 16 + lr) * 64 + kk * 32 + lk];
#pragma unroll
      for (int m = 0; m < 4; ++m)
#pragma unroll
        for (int n = 0; n < 4; ++n)
          acc[m][n] = __builtin_amdgcn_mfma_f32_16x16x32_bf16(af[m], bfr[n], acc[m][n], 0, 0, 0);
    }
  }
  const int r0 = bm + wr + (lane >> 4) * 4;
  const int c0 = bn + wc + lr;
#pragma unroll
  for (int m = 0; m < 4; ++m)
#pragma unroll
    for (int n = 0; n < 4; ++n) {
      int col = c0 + n * 16;
      float bb = bias ? bias[col] : 0.0f;
#pragma unroll
      for (int r = 0; r < 4; ++r) {
        float val = acc[m][n][r] + bb;
        size_t idx = (size_t)(r0 + m * 16 + r) * N + col;
        if (out_bf16)
          ((unsigned short*)Cout)[idx] = f2b(val);
        else
          ((float*)Cout)[idx] = val;
      }
    }
}

// bias + RoPE + scatter into attention layouts; K/V also to f32 outputs.
__global__ __launch_bounds__(256) void rope_scatter(
    const unsigned short* __restrict__ cqkv, const float* __restrict__ bq,
    const float* __restrict__ bk, const float* __restrict__ bv,
    const float* __restrict__ cosp, const float* __restrict__ sinp,
    unsigned short* __restrict__ qbuf, unsigned short* __restrict__ kbuf,
    unsigned short* __restrict__ vbuf, float* __restrict__ kout,
    float* __restrict__ vout) {
  const int bt = blockIdx.x;
  const int b = bt >> 11;
  const int t = bt & 2047;
  const int tid = threadIdx.x;
  const unsigned short* row = cqkv + (size_t)bt * 3072;

  for (int p = tid; p < 1024; p += 256) {
    int h = p >> 5, i = p & 31;
    float c = cosp[t * 32 + i], s = sinp[t * 32 + i];
    float q0 = b2f(row[2 * p]) + bq[2 * p];
    float q1 = b2f(row[2 * p + 1]) + bq[2 * p + 1];
    float qe = (q0 * c - q1 * s) * 0.125f;
    float qo = (q0 * s + q1 * c) * 0.125f;
    size_t base = ((size_t)(b * H_ + h) * T_ + t) * HD_ + 2 * i;
    qbuf[base] = f2b(qe);
    qbuf[base + 1] = f2b(qo);
  }
  {
    int p = tid;
    if (p < 256) {
      int kvh = p >> 5, i = p & 31;
      float c = cosp[t * 32 + i], s = sinp[t * 32 + i];
      float k0 = b2f(row[2048 + 2 * p]) + bk[2 * p];
      float k1 = b2f(row[2048 + 2 * p + 1]) + bk[2 * p + 1];
      float ke = k0 * c - k1 * s;
      float ko = k0 * s + k1 * c;
      size_t base = ((size_t)(b * KV_ + kvh) * T_ + t) * HD_ + 2 * i;
      kout[base] = ke;
      kout[base + 1] = ko;
      kbuf[base] = f2b(ke);
      kbuf[base + 1] = f2b(ko);
    }
  }
  for (int j = tid; j < 512; j += 256) {
    int kvh = j >> 6, d = j & 63;
    float v = b2f(row[2560 + j]) + bv[j];
    size_t base = ((size_t)(b * KV_ + kvh) * T_ + t) * HD_ + d;
    vout[base] = v;
    vbuf[base] = f2b(v);
  }
}

// Tiled transpose: vbuf[bk][t][d] -> vtb[bk][d][t].  grid(T/64, B*KV), 256 thr.
__global__ __launch_bounds__(256) void transpose_v(const unsigned short* __restrict__ vbuf,
                                                   unsigned short* __restrict__ vtb) {
  __shared__ unsigned short tile[64][72];
  const int tid = threadIdx.x;
  const int bk = blockIdx.y;
  const int t0 = blockIdx.x * 64;
  const unsigned short* src = vbuf + ((size_t)bk * T_ + t0) * HD_;
#pragma unroll
  for (int it = 0; it < 2; ++it) {
    int c = it * 256 + tid;
    int r = c >> 3;
    int c8 = (c & 7) * 8;
    *(bf16x8*)&tile[r][c8] = *(const bf16x8*)(src + (size_t)r * HD_ + c8);
  }
  __syncthreads();
  unsigned short* dst = vtb + (size_t)bk * HD_ * T_;
#pragma unroll
  for (int it = 0; it < 2; ++it) {
    int o = it * 256 + tid;
    int d = o >> 3;
    int t8 = (o & 7) * 8;
    bf16x8 v;
#pragma unroll
    for (int j = 0; j < 8; ++j) v[j] = (short)tile[t8 + j][d];
    *(bf16x8*)(dst + (size_t)d * T_ + t0 + t8) = v;
  }
}

// Causal GQA flash attention — barrier-free, paired q-tiles (uniform block cost),
// batched K/V fragment loads per kv-iteration.
// grid(NT/2, H, B), 256 thr = 4 waves x 16 q-rows. NT = T/64 = 32.
__global__ __launch_bounds__(256) void attn(const unsigned short* __restrict__ Q,
                                            const unsigned short* __restrict__ Kb,
                                            const unsigned short* __restrict__ Vtb,
                                            unsigned short* __restrict__ ctx) {
  __shared__ short Pw[4][16 * 72];
  const int j = blockIdx.x;          // pair index: tiles j and 31-j -> 33 iters/block
  const int h = blockIdx.y, bz = blockIdx.z;
  const int kvh = h >> 2;
  const int tid = threadIdx.x, lane = tid & 63, w = tid >> 6;
  const int lr = lane & 15;
  const int lk = (lane >> 4) * 8;
  const float NEGINF = -__builtin_inff();

  const unsigned short* kb = Kb + (size_t)(bz * KV_ + kvh) * T_ * HD_;
  const unsigned short* vt = Vtb + (size_t)(bz * KV_ + kvh) * HD_ * T_;  // [d][t]

  for (int phase = 0; phase < 2; ++phase) {
    const int qtile = phase ? (31 - j) : j;

    const unsigned short* qbase =
        Q + ((size_t)(bz * H_ + h) * T_ + qtile * 64 + w * 16) * HD_;
    bf16x8 qf0 = *(const bf16x8*)(qbase + (size_t)lr * HD_ + lk);
    bf16x8 qf1 = *(const bf16x8*)(qbase + (size_t)lr * HD_ + 32 + lk);

    float mrun[4] = {NEGINF, NEGINF, NEGINF, NEGINF};
    float lrun[4] = {0.f, 0.f, 0.f, 0.f};
    f32x4 acc[4] = {};

    for (int kt = 0; kt <= qtile; ++kt) {
      // batched fragment loads: all K and V issued up front (one vmcnt cluster;
      // V latency hides under softmax)
      const unsigned short* kp = kb + (size_t)kt * 64 * HD_;
      const unsigned short* vp = vt + (size_t)kt * 64;
      bf16x8 kf[8], vf[8];
#pragma unroll
      for (int cb = 0; cb < 4; ++cb) {
        kf[cb * 2]     = *(const bf16x8*)(kp + (size_t)(cb * 16 + lr) * HD_ + lk);
        kf[cb * 2 + 1] = *(const bf16x8*)(kp + (size_t)(cb * 16 + lr) * HD_ + 32 + lk);
        vf[cb * 2]     = *(const bf16x8*)(vp + (size_t)(cb * 16 + lr) * T_ + lk);
        vf[cb * 2 + 1] = *(const bf16x8*)(vp + (size_t)(cb * 16 + lr) * T_ + 32 + lk);
      }

      // scores: S[16 q][64 kv] per wave
      f32x4 s[4];
#pragma unroll
      for (int cb = 0; cb < 4; ++cb) {
        s[cb] = (f32x4){0.f, 0.f, 0.f, 0.f};
        s[cb] = __builtin_amdgcn_mfma_f32_16x16x32_bf16(qf0, kf[cb * 2], s[cb], 0, 0, 0);
        s[cb] = __builtin_amdgcn_mfma_f32_16x16x32_bf16(qf1, kf[cb * 2 + 1], s[cb], 0, 0, 0);
      }
      if (kt == qtile) {  // causal mask on diagonal tile
#pragma unroll
        for (int cb = 0; cb < 4; ++cb) {
          int col = cb * 16 + lr;
#pragma unroll
          for (int r = 0; r < 4; ++r) {
            int rowq = w * 16 + (lane >> 4) * 4 + r;
            if (col > rowq) s[cb][r] = NEGINF;
          }
        }
      }
      // online softmax (rows live in 16-lane groups)
#pragma unroll
      for (int r = 0; r < 4; ++r) {
        float v = fmaxf(fmaxf(s[0][r], s[1][r]), fmaxf(s[2][r], s[3][r]));
        v = fmaxf(v, __shfl_xor(v, 1));
        v = fmaxf(v, __shfl_xor(v, 2));
        v = fmaxf(v, __shfl_xor(v, 4));
        v = fmaxf(v, __shfl_xor(v, 8));
        float mnew = fmaxf(mrun[r], v);
        float sc = __expf(mrun[r] - mnew);
        mrun[r] = mnew;
        float ps = 0.f;
#pragma unroll
        for (int cb = 0; cb < 4; ++cb) {
          float p = __expf(s[cb][r] - mnew);
          s[cb][r] = p;
          ps += p;
        }
        ps += __shfl_xor(ps, 1);
        ps += __shfl_xor(ps, 2);
        ps += __shfl_xor(ps, 4);
        ps += __shfl_xor(ps, 8);
        lrun[r] = lrun[r] * sc + ps;
#pragma unroll
        for (int cb = 0; cb < 4; ++cb) {
          acc[cb][r] *= sc;
          Pw[w][((lane >> 4) * 4 + r) * 72 + cb * 16 + lr] = (short)f2b(s[cb][r]);
        }
      }
      // PV: ctx[16 q][64 hd] += P[16][64] @ V[64][64]  (V frags already resident)
      bf16x8 pa0 = *(const bf16x8*)&Pw[w][lr * 72 + lk];
      bf16x8 pa1 = *(const bf16x8*)&Pw[w][lr * 72 + 32 + lk];
#pragma unroll
      for (int cb = 0; cb < 4; ++cb) {
        acc[cb] = __builtin_amdgcn_mfma_f32_16x16x32_bf16(pa0, vf[cb * 2], acc[cb], 0, 0, 0);
        acc[cb] = __builtin_amdgcn_mfma_f32_16x16x32_bf16(pa1, vf[cb * 2 + 1], acc[cb], 0, 0, 0);
      }
    }
    // epilogue: ctx[b][t][h*64+d] bf16
#pragma unroll
    for (int cb = 0; cb < 4; ++cb)
#pragma unroll
      for (int r = 0; r < 4; ++r) {
        int rowq = qtile * 64 + w * 16 + (lane >> 4) * 4 + r;
        ctx[((size_t)bz * T_ + rowq) * DIN + h * HD_ + cb * 16 + lr] =
            f2b(acc[cb][r] / lrun[r]);
      }
  }
}

extern "C" void kernel_launch(void* const* d_in, const int* in_sizes, int n_in,
                              void* d_out, int out_size, void* d_ws, size_t ws_size,
                              hipStream_t stream) {
  const float* x = (const float*)d_in[0];
  const float* cosp = (const float*)d_in[1];
  const float* sinp = (const float*)d_in[2];
  const float* wq = (const float*)d_in[3];
  const float* bq = (const float*)d_in[4];
  const float* wk = (const float*)d_in[5];
  const float* bk = (const float*)d_in[6];
  const float* wv = (const float*)d_in[7];
  const float* bv = (const float*)d_in[8];
  const float* wo = (const float*)d_in[9];
  const float* bo = (const float*)d_in[10];

  float* out = (float*)d_out;
  float* kout = out + (size_t)B_ * T_ * DIN;
  float* vout = kout + (size_t)B_ * KV_ * T_ * HD_;

  // Workspace layout with reuse (peak 60 MB):
  //   region A @ 0MB  (16MB): xb      -> qbuf  (xb dead after gemm1)
  //   region B @ 16MB (12MB): wqkv    -> kbuf+vbuf (wqkv dead after gemm1)
  //   region C @ 28MB ( 8MB): wob     (static)
  //   region D @ 36MB (24MB): cqkv bf16 -> ctxb(36..52) + vtb(52..56)
  char* ws = (char*)d_ws;
  unsigned short* xb   = (unsigned short*)(ws + 0);
  unsigned short* wqkv = (unsigned short*)(ws + (size_t)16 * 1024 * 1024);
  unsigned short* wob  = (unsigned short*)(ws + (size_t)28 * 1024 * 1024);
  unsigned short* cqkv = (unsigned short*)(ws + (size_t)36 * 1024 * 1024);

  unsigned short* qbuf = xb;
  unsigned short* kbuf = wqkv;
  unsigned short* vbuf = wqkv + (size_t)2097152;
  unsigned short* ctxb = cqkv;
  unsigned short* vtb  = (unsigned short*)(ws + (size_t)52 * 1024 * 1024);

  // f32 -> bf16 conversions
  cvt_bf16<<<8192, 256, 0, stream>>>(x, xb, 2097152);
  cvt_bf16<<<4096, 256, 0, stream>>>(wq, wqkv, 1048576);
  cvt_bf16<<<1024, 256, 0, stream>>>(wk, wqkv + (size_t)2048 * 2048, 262144);
  cvt_bf16<<<1024, 256, 0, stream>>>(wv, wqkv + (size_t)2048 * 2048 + (size_t)512 * 2048, 262144);
  cvt_bf16<<<4096, 256, 0, stream>>>(wo, wob, 1048576);

  // QKV projection: (4096 x 2048) @ (3072 x 2048)^T -> bf16 cqkv
  gemm_bt<<<dim3(24, 32), 256, 0, stream>>>(xb, wqkv, nullptr, cqkv, 4096, 3072, 2048, 1);

  // bias + RoPE + scatter
  rope_scatter<<<4096, 256, 0, stream>>>(cqkv, bq, bk, bv, cosp, sinp, qbuf, kbuf,
                                         vbuf, kout, vout);

  // V transpose: vbuf[t][d] -> vtb[d][t]
  transpose_v<<<dim3(T_ / 64, B_ * KV_), 256, 0, stream>>>(vbuf, vtb);

  // causal GQA flash attention (paired q-tiles, uniform block cost)
  attn<<<dim3(T_ / 128, H_, B_), 256, 0, stream>>>(qbuf, kbuf, vtb, ctxb);

  // output projection: (4096 x 2048) @ (2048 x 2048)^T + bo -> f32 out
  gemm_bt<<<dim3(16, 32), 256, 0, stream>>>(ctxb, wob, bo, out, 4096, 2048, 2048, 0);
}

// Round 8
// 542.212 us; speedup vs baseline: 1.4075x; 1.0261x over previous
//
#include <hip/hip_runtime.h>
#include <cstdint>
#include <cstddef>

typedef short bf16x8 __attribute__((ext_vector_type(8)));
typedef float f32x4 __attribute__((ext_vector_type(4)));
typedef float f32x16 __attribute__((ext_vector_type(16)));

#define B_ 2
#define T_ 2048
#define DIN 2048
#define H_ 32
#define HD_ 64
#define KV_ 8

__device__ __forceinline__ unsigned short f2b(float f) {
  unsigned int u = __float_as_uint(f);
  u += 0x7fffu + ((u >> 16) & 1u);
  return (unsigned short)(u >> 16);
}

__device__ __forceinline__ float b2f(unsigned short b) {
  return __uint_as_float(((unsigned int)b) << 16);
}

__device__ __forceinline__ unsigned cvtpk_bf16(float lo, float hi) {
  unsigned r;
  asm("v_cvt_pk_bf16_f32 %0, %1, %2" : "=v"(r) : "v"(lo), "v"(hi));
  return r;
}

__device__ __forceinline__ void gload_lds16(const void* g, void* l) {
  __builtin_amdgcn_global_load_lds(
      (const unsigned int __attribute__((address_space(1)))*)g,
      (unsigned int __attribute__((address_space(3)))*)l, 16, 0, 0);
}

__global__ __launch_bounds__(256) void cvt_bf16(const float* __restrict__ in,
                                                unsigned short* __restrict__ out,
                                                int n4) {
  int i = blockIdx.x * 256 + threadIdx.x;
  if (i >= n4) return;
  float4 v = ((const float4*)in)[i];
  uint2 o;
  o.x = (unsigned)f2b(v.x) | ((unsigned)f2b(v.y) << 16);
  o.y = (unsigned)f2b(v.z) | ((unsigned)f2b(v.w) << 16);
  ((uint2*)out)[i] = o;
}

// C[M][N] = A[M][K] * Bw[N][K]^T (+bias). bf16 inputs; f32 or bf16 out.
__global__ __launch_bounds__(256) void gemm_bt(const unsigned short* __restrict__ A,
                                               const unsigned short* __restrict__ Bw,
                                               const float* __restrict__ bias,
                                               void* __restrict__ Cout,
                                               int M, int N, int K, int out_bf16) {
  __shared__ short As[128 * 64];
  __shared__ short Bs[128 * 64];
  const int tid = threadIdx.x;
  const int lane = tid & 63;
  const int wid = tid >> 6;
  const int wr = (wid >> 1) * 64;
  const int wc = (wid & 1) * 64;
  const int bm = blockIdx.y * 128;
  const int bn = blockIdx.x * 128;
  const int lr = lane & 15;
  const int lk = (lane >> 4) * 8;
  f32x4 acc[4][4] = {};

  for (int kt = 0; kt < K; kt += 64) {
    __syncthreads();
#pragma unroll
    for (int it = 0; it < 4; ++it) {
      int c = it * 256 + tid;
      int r = c >> 3;
      int c8 = (c & 7) * 8;
      gload_lds16(A + (size_t)(bm + r) * K + kt + c8, &As[c * 8]);
      gload_lds16(Bw + (size_t)(bn + r) * K + kt + c8, &Bs[c * 8]);
    }
    __syncthreads();
#pragma unroll
    for (int kk = 0; kk < 2; ++kk) {
      bf16x8 af[4], bfr[4];
#pragma unroll
      for (int m = 0; m < 4; ++m)
        af[m] = *(const bf16x8*)&As[(wr + m * 16 + lr) * 64 + kk * 32 + lk];
#pragma unroll
      for (int n = 0; n < 4; ++n)
        bfr[n] = *(const bf16x8*)&Bs[(wc + n * 16 + lr) * 64 + kk * 32 + lk];
#pragma unroll
      for (int m = 0; m < 4; ++m)
#pragma unroll
        for (int n = 0; n < 4; ++n)
          acc[m][n] = __builtin_amdgcn_mfma_f32_16x16x32_bf16(af[m], bfr[n], acc[m][n], 0, 0, 0);
    }
  }
  const int r0 = bm + wr + (lane >> 4) * 4;
  const int c0 = bn + wc + lr;
#pragma unroll
  for (int m = 0; m < 4; ++m)
#pragma unroll
    for (int n = 0; n < 4; ++n) {
      int col = c0 + n * 16;
      float bb = bias ? bias[col] : 0.0f;
#pragma unroll
      for (int r = 0; r < 4; ++r) {
        float val = acc[m][n][r] + bb;
        size_t idx = (size_t)(r0 + m * 16 + r) * N + col;
        if (out_bf16)
          ((unsigned short*)Cout)[idx] = f2b(val);
        else
          ((float*)Cout)[idx] = val;
      }
    }
}

// bias + RoPE + scatter into attention layouts; K/V also to f32 outputs.
__global__ __launch_bounds__(256) void rope_scatter(
    const unsigned short* __restrict__ cqkv, const float* __restrict__ bq,
    const float* __restrict__ bk, const float* __restrict__ bv,
    const float* __restrict__ cosp, const float* __restrict__ sinp,
    unsigned short* __restrict__ qbuf, unsigned short* __restrict__ kbuf,
    unsigned short* __restrict__ vbuf, float* __restrict__ kout,
    float* __restrict__ vout) {
  const int bt = blockIdx.x;
  const int b = bt >> 11;
  const int t = bt & 2047;
  const int tid = threadIdx.x;
  const unsigned short* row = cqkv + (size_t)bt * 3072;

  for (int p = tid; p < 1024; p += 256) {
    int h = p >> 5, i = p & 31;
    float c = cosp[t * 32 + i], s = sinp[t * 32 + i];
    float q0 = b2f(row[2 * p]) + bq[2 * p];
    float q1 = b2f(row[2 * p + 1]) + bq[2 * p + 1];
    float qe = (q0 * c - q1 * s) * 0.125f;
    float qo = (q0 * s + q1 * c) * 0.125f;
    size_t base = ((size_t)(b * H_ + h) * T_ + t) * HD_ + 2 * i;
    qbuf[base] = f2b(qe);
    qbuf[base + 1] = f2b(qo);
  }
  {
    int p = tid;
    if (p < 256) {
      int kvh = p >> 5, i = p & 31;
      float c = cosp[t * 32 + i], s = sinp[t * 32 + i];
      float k0 = b2f(row[2048 + 2 * p]) + bk[2 * p];
      float k1 = b2f(row[2048 + 2 * p + 1]) + bk[2 * p + 1];
      float ke = k0 * c - k1 * s;
      float ko = k0 * s + k1 * c;
      size_t base = ((size_t)(b * KV_ + kvh) * T_ + t) * HD_ + 2 * i;
      kout[base] = ke;
      kout[base + 1] = ko;
      kbuf[base] = f2b(ke);
      kbuf[base + 1] = f2b(ko);
    }
  }
  for (int j = tid; j < 512; j += 256) {
    int kvh = j >> 6, d = j & 63;
    float v = b2f(row[2560 + j]) + bv[j];
    size_t base = ((size_t)(b * KV_ + kvh) * T_ + t) * HD_ + d;
    vout[base] = v;
    vbuf[base] = f2b(v);
  }
}

// Tiled transpose: vbuf[bk][t][d] -> vtb[bk][d][t].  grid(T/64, B*KV), 256 thr.
__global__ __launch_bounds__(256) void transpose_v(const unsigned short* __restrict__ vbuf,
                                                   unsigned short* __restrict__ vtb) {
  __shared__ unsigned short tile[64][72];
  const int tid = threadIdx.x;
  const int bk = blockIdx.y;
  const int t0 = blockIdx.x * 64;
  const unsigned short* src = vbuf + ((size_t)bk * T_ + t0) * HD_;
#pragma unroll
  for (int it = 0; it < 2; ++it) {
    int c = it * 256 + tid;
    int r = c >> 3;
    int c8 = (c & 7) * 8;
    *(bf16x8*)&tile[r][c8] = *(const bf16x8*)(src + (size_t)r * HD_ + c8);
  }
  __syncthreads();
  unsigned short* dst = vtb + (size_t)bk * HD_ * T_;
#pragma unroll
  for (int it = 0; it < 2; ++it) {
    int o = it * 256 + tid;
    int d = o >> 3;
    int t8 = (o & 7) * 8;
    bf16x8 v;
#pragma unroll
    for (int j = 0; j < 8; ++j) v[j] = (short)tile[t8 + j][d];
    *(bf16x8*)(dst + (size_t)d * T_ + t0 + t8) = v;
  }
}

// ---------------------------------------------------------------------------
// Causal GQA flash attention, swapped-QK^T 32x32 structure (m214-style):
// one wave = one 32-row q-tile, full D=64. S^T = K·Q^T via mfma_32x32x16 so
// each lane owns a whole softmax row (q = lane&31): max/sum are in-lane VALU,
// P->A-fragment via cvt_pk_bf16 + permlane32_swap. No LDS, no barriers.
// grid(16, H, B), 256 thr = 4 waves; wave w handles qt = 63 - (bx*4+w).
// ---------------------------------------------------------------------------
__global__ __launch_bounds__(256) void attn(const unsigned short* __restrict__ Q,
                                            const unsigned short* __restrict__ Kb,
                                            const unsigned short* __restrict__ Vtb,
                                            unsigned short* __restrict__ ctx) {
  const int h = blockIdx.y, bz = blockIdx.z;
  const int kvh = h >> 2;
  const int tid = threadIdx.x, lane = tid & 63, w = tid >> 6;
  const int qt = 63 - ((int)blockIdx.x * 4 + w);  // heavy tiles dispatched first
  const int q0 = qt * 32;
  const int l31 = lane & 31, hi = lane >> 5;
  const float NEGINF = -__builtin_inff();

  const unsigned short* qb = Q + ((size_t)(bz * H_ + h) * T_ + q0) * HD_;
  const unsigned short* kb = Kb + (size_t)(bz * KV_ + kvh) * T_ * HD_;
  const unsigned short* vt = Vtb + (size_t)(bz * KV_ + kvh) * HD_ * T_;  // [d][t]

  // Q fragments (B-operand: col=q=l31, k=d), hoisted for all iterations.
  bf16x8 qf[4];
#pragma unroll
  for (int ds = 0; ds < 4; ++ds)
    qf[ds] = *(const bf16x8*)(qb + (size_t)l31 * HD_ + ds * 16 + hi * 8);

  float mrun = NEGINF, lp = 0.f;
  f32x16 oa0 = {}, oa1 = {};
  const int niter = (qt >> 1) + 1;
  const bool evenq = (qt & 1) == 0;

  for (int it = 0; it < niter; ++it) {
    const bool last = (it == niter - 1);
    const bool skip1 = last && evenq;  // upper 32-kv half fully masked
    const int kvb = it * 64;
    const unsigned short* kp = kb + (size_t)kvb * HD_;
    const unsigned short* vp = vt + kvb;

    // K fragments (A-operand: row=kv, k=d)
    bf16x8 kf0[4], kf1[4];
#pragma unroll
    for (int ds = 0; ds < 4; ++ds)
      kf0[ds] = *(const bf16x8*)(kp + (size_t)l31 * HD_ + ds * 16 + hi * 8);
    if (!skip1) {
#pragma unroll
      for (int ds = 0; ds < 4; ++ds)
        kf1[ds] = *(const bf16x8*)(kp + (size_t)(32 + l31) * HD_ + ds * 16 + hi * 8);
    }
    // V fragments (B-operand for PV: col=d, k=kv), issued early to hide latency
    bf16x8 vf0[4], vf1[4];
#pragma unroll
    for (int ks = 0; ks < 2; ++ks) {
      vf0[ks] = *(const bf16x8*)(vp + (size_t)l31 * T_ + ks * 16 + hi * 8);
      vf1[ks] = *(const bf16x8*)(vp + (size_t)(32 + l31) * T_ + ks * 16 + hi * 8);
    }
    if (!skip1) {
#pragma unroll
      for (int ks = 2; ks < 4; ++ks) {
        vf0[ks] = *(const bf16x8*)(vp + (size_t)l31 * T_ + ks * 16 + hi * 8);
        vf1[ks] = *(const bf16x8*)(vp + (size_t)(32 + l31) * T_ + ks * 16 + hi * 8);
      }
    }

    // S^T tiles: D[kv][q] = K·Q^T
    f32x16 s0 = {}, s1 = {};
#pragma unroll
    for (int ds = 0; ds < 4; ++ds)
      s0 = __builtin_amdgcn_mfma_f32_32x32x16_bf16(kf0[ds], qf[ds], s0, 0, 0, 0);
    if (!skip1) {
#pragma unroll
      for (int ds = 0; ds < 4; ++ds)
        s1 = __builtin_amdgcn_mfma_f32_32x32x16_bf16(kf1[ds], qf[ds], s1, 0, 0, 0);
    }

    // causal mask on the diagonal 32-kv half (local cond: crow > q-col)
    if (last) {
#pragma unroll
      for (int r = 0; r < 16; ++r) {
        int cr = (r & 3) + 8 * (r >> 2) + 4 * hi;
        if (evenq)
          s0[r] = (cr > l31) ? NEGINF : s0[r];
        else
          s1[r] = (cr > l31) ? NEGINF : s1[r];
      }
    }

    // row max: in-lane tree + one cross-half exchange
    float a = fmaxf(fmaxf(s0[0], s0[1]), fmaxf(s0[2], s0[3]));
    float b = fmaxf(fmaxf(s0[4], s0[5]), fmaxf(s0[6], s0[7]));
    float c = fmaxf(fmaxf(s0[8], s0[9]), fmaxf(s0[10], s0[11]));
    float d = fmaxf(fmaxf(s0[12], s0[13]), fmaxf(s0[14], s0[15]));
    float tm = fmaxf(fmaxf(a, b), fmaxf(c, d));
    if (!skip1) {
      float a1 = fmaxf(fmaxf(s1[0], s1[1]), fmaxf(s1[2], s1[3]));
      float b1 = fmaxf(fmaxf(s1[4], s1[5]), fmaxf(s1[6], s1[7]));
      float c1 = fmaxf(fmaxf(s1[8], s1[9]), fmaxf(s1[10], s1[11]));
      float d1 = fmaxf(fmaxf(s1[12], s1[13]), fmaxf(s1[14], s1[15]));
      tm = fmaxf(tm, fmaxf(fmaxf(a1, b1), fmaxf(c1, d1)));
    }
    tm = fmaxf(tm, __shfl_xor(tm, 32));

    // defer-max (THR=8): rescale only when some row's max grew past threshold
    if (!__all(tm - mrun <= 8.0f)) {
      float mnew = fmaxf(mrun, tm);
      float sc = __expf(mrun - mnew);
      lp *= sc;
#pragma unroll
      for (int i = 0; i < 16; ++i) {
        oa0[i] *= sc;
        oa1[i] *= sc;
      }
      mrun = mnew;
    }

    // exp + per-lane partial row sum
    float pe0[16], pe1[16];
    float ls = 0.f;
#pragma unroll
    for (int r = 0; r < 16; ++r) {
      pe0[r] = __expf(s0[r] - mrun);
      ls += pe0[r];
    }
    if (!skip1) {
#pragma unroll
      for (int r = 0; r < 16; ++r) {
        pe1[r] = __expf(s1[r] - mrun);
        ls += pe1[r];
      }
    }
    lp += ls;

    // pack P into A-fragments: 4 cvt_pk + 2 permlane32_swap per k-step
    union {
      unsigned u[4];
      bf16x8 v;
    } pa[4];
#pragma unroll
    for (int ks2 = 0; ks2 < 2; ++ks2) {
      unsigned c0 = cvtpk_bf16(pe0[8 * ks2 + 0], pe0[8 * ks2 + 1]);
      unsigned c1 = cvtpk_bf16(pe0[8 * ks2 + 2], pe0[8 * ks2 + 3]);
      unsigned c2 = cvtpk_bf16(pe0[8 * ks2 + 4], pe0[8 * ks2 + 5]);
      unsigned c3 = cvtpk_bf16(pe0[8 * ks2 + 6], pe0[8 * ks2 + 7]);
      asm("v_permlane32_swap_b32 %0, %1" : "+v"(c0), "+v"(c2));
      asm("v_permlane32_swap_b32 %0, %1" : "+v"(c1), "+v"(c3));
      pa[ks2].u[0] = c0;
      pa[ks2].u[1] = c1;
      pa[ks2].u[2] = c2;
      pa[ks2].u[3] = c3;
    }
    if (!skip1) {
#pragma unroll
      for (int ks2 = 0; ks2 < 2; ++ks2) {
        unsigned c0 = cvtpk_bf16(pe1[8 * ks2 + 0], pe1[8 * ks2 + 1]);
        unsigned c1 = cvtpk_bf16(pe1[8 * ks2 + 2], pe1[8 * ks2 + 3]);
        unsigned c2 = cvtpk_bf16(pe1[8 * ks2 + 4], pe1[8 * ks2 + 5]);
        unsigned c3 = cvtpk_bf16(pe1[8 * ks2 + 6], pe1[8 * ks2 + 7]);
        asm("v_permlane32_swap_b32 %0, %1" : "+v"(c0), "+v"(c2));
        asm("v_permlane32_swap_b32 %0, %1" : "+v"(c1), "+v"(c3));
        pa[2 + ks2].u[0] = c0;
        pa[2 + ks2].u[1] = c1;
        pa[2 + ks2].u[2] = c2;
        pa[2 + ks2].u[3] = c3;
      }
    }

    // PV: O[q][d] += P·V
#pragma unroll
    for (int ks = 0; ks < 2; ++ks) {
      oa0 = __builtin_amdgcn_mfma_f32_32x32x16_bf16(pa[ks].v, vf0[ks], oa0, 0, 0, 0);
      oa1 = __builtin_amdgcn_mfma_f32_32x32x16_bf16(pa[ks].v, vf1[ks], oa1, 0, 0, 0);
    }
    if (!skip1) {
#pragma unroll
      for (int ks = 2; ks < 4; ++ks) {
        oa0 = __builtin_amdgcn_mfma_f32_32x32x16_bf16(pa[ks].v, vf0[ks], oa0, 0, 0, 0);
        oa1 = __builtin_amdgcn_mfma_f32_32x32x16_bf16(pa[ks].v, vf1[ks], oa1, 0, 0, 0);
      }
    }
  }

  // epilogue: row-sum finalize (one exchange), broadcast per output row, store
  float lt = lp + __shfl_xor(lp, 32);
#pragma unroll
  for (int r = 0; r < 16; ++r) {
    int cr = (r & 3) + 8 * (r >> 2) + 4 * hi;
    float lrow = __shfl(lt, cr);
    float inv = 1.0f / lrow;
    size_t base = ((size_t)bz * T_ + q0 + cr) * DIN + h * HD_;
    ctx[base + l31] = f2b(oa0[r] * inv);
    ctx[base + 32 + l31] = f2b(oa1[r] * inv);
  }
}

extern "C" void kernel_launch(void* const* d_in, const int* in_sizes, int n_in,
                              void* d_out, int out_size, void* d_ws, size_t ws_size,
                              hipStream_t stream) {
  const float* x = (const float*)d_in[0];
  const float* cosp = (const float*)d_in[1];
  const float* sinp = (const float*)d_in[2];
  const float* wq = (const float*)d_in[3];
  const float* bq = (const float*)d_in[4];
  const float* wk = (const float*)d_in[5];
  const float* bk = (const float*)d_in[6];
  const float* wv = (const float*)d_in[7];
  const float* bv = (const float*)d_in[8];
  const float* wo = (const float*)d_in[9];
  const float* bo = (const float*)d_in[10];

  float* out = (float*)d_out;
  float* kout = out + (size_t)B_ * T_ * DIN;
  float* vout = kout + (size_t)B_ * KV_ * T_ * HD_;

  // Workspace layout with reuse (peak 60 MB):
  //   region A @ 0MB  (16MB): xb      -> qbuf  (xb dead after gemm1)
  //   region B @ 16MB (12MB): wqkv    -> kbuf+vbuf (wqkv dead after gemm1)
  //   region C @ 28MB ( 8MB): wob     (static)
  //   region D @ 36MB (24MB): cqkv bf16 -> ctxb(36..52) + vtb(52..56)
  char* ws = (char*)d_ws;
  unsigned short* xb   = (unsigned short*)(ws + 0);
  unsigned short* wqkv = (unsigned short*)(ws + (size_t)16 * 1024 * 1024);
  unsigned short* wob  = (unsigned short*)(ws + (size_t)28 * 1024 * 1024);
  unsigned short* cqkv = (unsigned short*)(ws + (size_t)36 * 1024 * 1024);

  unsigned short* qbuf = xb;
  unsigned short* kbuf = wqkv;
  unsigned short* vbuf = wqkv + (size_t)2097152;
  unsigned short* ctxb = cqkv;
  unsigned short* vtb  = (unsigned short*)(ws + (size_t)52 * 1024 * 1024);

  // f32 -> bf16 conversions
  cvt_bf16<<<8192, 256, 0, stream>>>(x, xb, 2097152);
  cvt_bf16<<<4096, 256, 0, stream>>>(wq, wqkv, 1048576);
  cvt_bf16<<<1024, 256, 0, stream>>>(wk, wqkv + (size_t)2048 * 2048, 262144);
  cvt_bf16<<<1024, 256, 0, stream>>>(wv, wqkv + (size_t)2048 * 2048 + (size_t)512 * 2048, 262144);
  cvt_bf16<<<4096, 256, 0, stream>>>(wo, wob, 1048576);

  // QKV projection: (4096 x 2048) @ (3072 x 2048)^T -> bf16 cqkv
  gemm_bt<<<dim3(24, 32), 256, 0, stream>>>(xb, wqkv, nullptr, cqkv, 4096, 3072, 2048, 1);

  // bias + RoPE + scatter
  rope_scatter<<<4096, 256, 0, stream>>>(cqkv, bq, bk, bv, cosp, sinp, qbuf, kbuf,
                                         vbuf, kout, vout);

  // V transpose: vbuf[t][d] -> vtb[d][t]
  transpose_v<<<dim3(T_ / 64, B_ * KV_), 256, 0, stream>>>(vbuf, vtb);

  // causal GQA flash attention (swapped-QK^T 32x32, in-register softmax)
  attn<<<dim3(16, H_, B_), 256, 0, stream>>>(qbuf, kbuf, vtb, ctxb);

  // output projection: (4096 x 2048) @ (2048 x 2048)^T + bo -> f32 out
  gemm_bt<<<dim3(16, 32), 256, 0, stream>>>(ctxb, wob, bo, out, 4096, 2048, 2048, 0);
}

// Round 9
// 445.422 us; speedup vs baseline: 1.7133x; 1.2173x over previous
//
#include <hip/hip_runtime.h>
#include <cstdint>
#include <cstddef>

typedef short bf16x8 __attribute__((ext_vector_type(8)));
typedef float f32x4 __attribute__((ext_vector_type(4)));
typedef float f32x16 __attribute__((ext_vector_type(16)));

#define B_ 2
#define T_ 2048
#define DIN 2048
#define H_ 32
#define HD_ 64
#define KV_ 8

__device__ __forceinline__ unsigned short f2b(float f) {
  unsigned int u = __float_as_uint(f);
  u += 0x7fffu + ((u >> 16) & 1u);
  return (unsigned short)(u >> 16);
}

__device__ __forceinline__ float b2f(unsigned short b) {
  return __uint_as_float(((unsigned int)b) << 16);
}

__device__ __forceinline__ unsigned cvtpk_bf16(float lo, float hi) {
  unsigned r;
  asm("v_cvt_pk_bf16_f32 %0, %1, %2" : "=v"(r) : "v"(lo), "v"(hi));
  return r;
}

__device__ __forceinline__ void gload_lds16(const void* g, void* l) {
  __builtin_amdgcn_global_load_lds(
      (const unsigned int __attribute__((address_space(1)))*)g,
      (unsigned int __attribute__((address_space(3)))*)l, 16, 0, 0);
}

__global__ __launch_bounds__(256) void cvt_bf16(const float* __restrict__ in,
                                                unsigned short* __restrict__ out,
                                                int n4) {
  int i = blockIdx.x * 256 + threadIdx.x;
  if (i >= n4) return;
  float4 v = ((const float4*)in)[i];
  uint2 o;
  o.x = (unsigned)f2b(v.x) | ((unsigned)f2b(v.y) << 16);
  o.y = (unsigned)f2b(v.z) | ((unsigned)f2b(v.w) << 16);
  ((uint2*)out)[i] = o;
}

// C[M][N] = A[M][K] * Bw[N][K]^T (+bias). bf16 inputs; f32 or bf16 out.
__global__ __launch_bounds__(256) void gemm_bt(const unsigned short* __restrict__ A,
                                               const unsigned short* __restrict__ Bw,
                                               const float* __restrict__ bias,
                                               void* __restrict__ Cout,
                                               int M, int N, int K, int out_bf16) {
  __shared__ short As[128 * 64];
  __shared__ short Bs[128 * 64];
  const int tid = threadIdx.x;
  const int lane = tid & 63;
  const int wid = tid >> 6;
  const int wr = (wid >> 1) * 64;
  const int wc = (wid & 1) * 64;
  const int bm = blockIdx.y * 128;
  const int bn = blockIdx.x * 128;
  const int lr = lane & 15;
  const int lk = (lane >> 4) * 8;
  f32x4 acc[4][4] = {};

  for (int kt = 0; kt < K; kt += 64) {
    __syncthreads();
#pragma unroll
    for (int it = 0; it < 4; ++it) {
      int c = it * 256 + tid;
      int r = c >> 3;
      int c8 = (c & 7) * 8;
      gload_lds16(A + (size_t)(bm + r) * K + kt + c8, &As[c * 8]);
      gload_lds16(Bw + (size_t)(bn + r) * K + kt + c8, &Bs[c * 8]);
    }
    __syncthreads();
#pragma unroll
    for (int kk = 0; kk < 2; ++kk) {
      bf16x8 af[4], bfr[4];
#pragma unroll
      for (int m = 0; m < 4; ++m)
        af[m] = *(const bf16x8*)&As[(wr + m * 16 + lr) * 64 + kk * 32 + lk];
#pragma unroll
      for (int n = 0; n < 4; ++n)
        bfr[n] = *(const bf16x8*)&Bs[(wc + n * 16 + lr) * 64 + kk * 32 + lk];
#pragma unroll
      for (int m = 0; m < 4; ++m)
#pragma unroll
        for (int n = 0; n < 4; ++n)
          acc[m][n] = __builtin_amdgcn_mfma_f32_16x16x32_bf16(af[m], bfr[n], acc[m][n], 0, 0, 0);
    }
  }
  const int r0 = bm + wr + (lane >> 4) * 4;
  const int c0 = bn + wc + lr;
#pragma unroll
  for (int m = 0; m < 4; ++m)
#pragma unroll
    for (int n = 0; n < 4; ++n) {
      int col = c0 + n * 16;
      float bb = bias ? bias[col] : 0.0f;
#pragma unroll
      for (int r = 0; r < 4; ++r) {
        float val = acc[m][n][r] + bb;
        size_t idx = (size_t)(r0 + m * 16 + r) * N + col;
        if (out_bf16)
          ((unsigned short*)Cout)[idx] = f2b(val);
        else
          ((float*)Cout)[idx] = val;
      }
    }
}

// bias + RoPE + scatter into attention layouts; K/V also to f32 outputs.
__global__ __launch_bounds__(256) void rope_scatter(
    const unsigned short* __restrict__ cqkv, const float* __restrict__ bq,
    const float* __restrict__ bk, const float* __restrict__ bv,
    const float* __restrict__ cosp, const float* __restrict__ sinp,
    unsigned short* __restrict__ qbuf, unsigned short* __restrict__ kbuf,
    unsigned short* __restrict__ vbuf, float* __restrict__ kout,
    float* __restrict__ vout) {
  const int bt = blockIdx.x;
  const int b = bt >> 11;
  const int t = bt & 2047;
  const int tid = threadIdx.x;
  const unsigned short* row = cqkv + (size_t)bt * 3072;

  for (int p = tid; p < 1024; p += 256) {
    int h = p >> 5, i = p & 31;
    float c = cosp[t * 32 + i], s = sinp[t * 32 + i];
    float q0 = b2f(row[2 * p]) + bq[2 * p];
    float q1 = b2f(row[2 * p + 1]) + bq[2 * p + 1];
    float qe = (q0 * c - q1 * s) * 0.125f;
    float qo = (q0 * s + q1 * c) * 0.125f;
    size_t base = ((size_t)(b * H_ + h) * T_ + t) * HD_ + 2 * i;
    qbuf[base] = f2b(qe);
    qbuf[base + 1] = f2b(qo);
  }
  {
    int p = tid;
    if (p < 256) {
      int kvh = p >> 5, i = p & 31;
      float c = cosp[t * 32 + i], s = sinp[t * 32 + i];
      float k0 = b2f(row[2048 + 2 * p]) + bk[2 * p];
      float k1 = b2f(row[2048 + 2 * p + 1]) + bk[2 * p + 1];
      float ke = k0 * c - k1 * s;
      float ko = k0 * s + k1 * c;
      size_t base = ((size_t)(b * KV_ + kvh) * T_ + t) * HD_ + 2 * i;
      kout[base] = ke;
      kout[base + 1] = ko;
      kbuf[base] = f2b(ke);
      kbuf[base + 1] = f2b(ko);
    }
  }
  for (int j = tid; j < 512; j += 256) {
    int kvh = j >> 6, d = j & 63;
    float v = b2f(row[2560 + j]) + bv[j];
    size_t base = ((size_t)(b * KV_ + kvh) * T_ + t) * HD_ + d;
    vout[base] = v;
    vbuf[base] = f2b(v);
  }
}

// Tiled transpose: vbuf[bk][t][d] -> vtb[bk][d][t].  grid(T/64, B*KV), 256 thr.
__global__ __launch_bounds__(256) void transpose_v(const unsigned short* __restrict__ vbuf,
                                                   unsigned short* __restrict__ vtb) {
  __shared__ unsigned short tile[64][72];
  const int tid = threadIdx.x;
  const int bk = blockIdx.y;
  const int t0 = blockIdx.x * 64;
  const unsigned short* src = vbuf + ((size_t)bk * T_ + t0) * HD_;
#pragma unroll
  for (int it = 0; it < 2; ++it) {
    int c = it * 256 + tid;
    int r = c >> 3;
    int c8 = (c & 7) * 8;
    *(bf16x8*)&tile[r][c8] = *(const bf16x8*)(src + (size_t)r * HD_ + c8);
  }
  __syncthreads();
  unsigned short* dst = vtb + (size_t)bk * HD_ * T_;
#pragma unroll
  for (int it = 0; it < 2; ++it) {
    int o = it * 256 + tid;
    int d = o >> 3;
    int t8 = (o & 7) * 8;
    bf16x8 v;
#pragma unroll
    for (int j = 0; j < 8; ++j) v[j] = (short)tile[t8 + j][d];
    *(bf16x8*)(dst + (size_t)d * T_ + t0 + t8) = v;
  }
}

// ---------------------------------------------------------------------------
// Causal GQA flash attention, swapped-QK^T 32x32 structure with qt-PAIRING:
// wave w of block bx takes j = bx*4+w in [0,32), processes qt = 63-j then j
// -> every wave exactly 33 kv-iters (uniform cost, zero tail).
// One wave = one 32-row q-tile, full D=64. S^T = K·Q^T via mfma_32x32x16 so
// each lane owns a whole softmax row (q = lane&31). In-register softmax,
// P->A-fragment via cvt_pk_bf16 + permlane32_swap. No LDS, no barriers.
// grid(8, H, B), 256 thr = 4 waves.
// ---------------------------------------------------------------------------
__global__ __launch_bounds__(256) void attn(const unsigned short* __restrict__ Q,
                                            const unsigned short* __restrict__ Kb,
                                            const unsigned short* __restrict__ Vtb,
                                            unsigned short* __restrict__ ctx) {
  const int h = blockIdx.y, bz = blockIdx.z;
  const int kvh = h >> 2;
  const int tid = threadIdx.x, lane = tid & 63, w = tid >> 6;
  const int jidx = (int)blockIdx.x * 4 + w;  // 0..31
  const int l31 = lane & 31, hi = lane >> 5;
  const float NEGINF = -__builtin_inff();

  const unsigned short* kb = Kb + (size_t)(bz * KV_ + kvh) * T_ * HD_;
  const unsigned short* vt = Vtb + (size_t)(bz * KV_ + kvh) * HD_ * T_;  // [d][t]

  for (int p2 = 0; p2 < 2; ++p2) {
    const int qt = p2 ? jidx : (63 - jidx);  // heavy tile first
    const int q0 = qt * 32;

    const unsigned short* qb = Q + ((size_t)(bz * H_ + h) * T_ + q0) * HD_;

    // Q fragments (B-operand: col=q=l31, k=d)
    bf16x8 qf[4];
#pragma unroll
    for (int ds = 0; ds < 4; ++ds)
      qf[ds] = *(const bf16x8*)(qb + (size_t)l31 * HD_ + ds * 16 + hi * 8);

    float mrun = NEGINF, lp = 0.f;
    f32x16 oa0 = {}, oa1 = {};
    const int niter = (qt >> 1) + 1;
    const bool evenq = (qt & 1) == 0;

    for (int it = 0; it < niter; ++it) {
      const bool last = (it == niter - 1);
      const bool skip1 = last && evenq;  // upper 32-kv half fully masked
      const int kvb = it * 64;
      const unsigned short* kp = kb + (size_t)kvb * HD_;
      const unsigned short* vp = vt + kvb;

      // K fragments (A-operand: row=kv, k=d)
      bf16x8 kf0[4], kf1[4];
#pragma unroll
      for (int ds = 0; ds < 4; ++ds)
        kf0[ds] = *(const bf16x8*)(kp + (size_t)l31 * HD_ + ds * 16 + hi * 8);
      if (!skip1) {
#pragma unroll
        for (int ds = 0; ds < 4; ++ds)
          kf1[ds] = *(const bf16x8*)(kp + (size_t)(32 + l31) * HD_ + ds * 16 + hi * 8);
      }
      // V fragments (B-operand for PV: col=d, k=kv), issued early to hide latency
      bf16x8 vf0[4], vf1[4];
#pragma unroll
      for (int ks = 0; ks < 2; ++ks) {
        vf0[ks] = *(const bf16x8*)(vp + (size_t)l31 * T_ + ks * 16 + hi * 8);
        vf1[ks] = *(const bf16x8*)(vp + (size_t)(32 + l31) * T_ + ks * 16 + hi * 8);
      }
      if (!skip1) {
#pragma unroll
        for (int ks = 2; ks < 4; ++ks) {
          vf0[ks] = *(const bf16x8*)(vp + (size_t)l31 * T_ + ks * 16 + hi * 8);
          vf1[ks] = *(const bf16x8*)(vp + (size_t)(32 + l31) * T_ + ks * 16 + hi * 8);
        }
      }

      // S^T tiles: D[kv][q] = K·Q^T
      f32x16 s0 = {}, s1 = {};
#pragma unroll
      for (int ds = 0; ds < 4; ++ds)
        s0 = __builtin_amdgcn_mfma_f32_32x32x16_bf16(kf0[ds], qf[ds], s0, 0, 0, 0);
      if (!skip1) {
#pragma unroll
        for (int ds = 0; ds < 4; ++ds)
          s1 = __builtin_amdgcn_mfma_f32_32x32x16_bf16(kf1[ds], qf[ds], s1, 0, 0, 0);
      }

      // causal mask on the diagonal 32-kv half (local cond: crow > q-col)
      if (last) {
#pragma unroll
        for (int r = 0; r < 16; ++r) {
          int cr = (r & 3) + 8 * (r >> 2) + 4 * hi;
          if (evenq)
            s0[r] = (cr > l31) ? NEGINF : s0[r];
          else
            s1[r] = (cr > l31) ? NEGINF : s1[r];
        }
      }

      // row max: in-lane tree + one cross-half exchange
      float a = fmaxf(fmaxf(s0[0], s0[1]), fmaxf(s0[2], s0[3]));
      float b = fmaxf(fmaxf(s0[4], s0[5]), fmaxf(s0[6], s0[7]));
      float c = fmaxf(fmaxf(s0[8], s0[9]), fmaxf(s0[10], s0[11]));
      float d = fmaxf(fmaxf(s0[12], s0[13]), fmaxf(s0[14], s0[15]));
      float tm = fmaxf(fmaxf(a, b), fmaxf(c, d));
      if (!skip1) {
        float a1 = fmaxf(fmaxf(s1[0], s1[1]), fmaxf(s1[2], s1[3]));
        float b1 = fmaxf(fmaxf(s1[4], s1[5]), fmaxf(s1[6], s1[7]));
        float c1 = fmaxf(fmaxf(s1[8], s1[9]), fmaxf(s1[10], s1[11]));
        float d1 = fmaxf(fmaxf(s1[12], s1[13]), fmaxf(s1[14], s1[15]));
        tm = fmaxf(tm, fmaxf(fmaxf(a1, b1), fmaxf(c1, d1)));
      }
      tm = fmaxf(tm, __shfl_xor(tm, 32));

      // defer-max (THR=8): rescale only when some row's max grew past threshold
      if (!__all(tm - mrun <= 8.0f)) {
        float mnew = fmaxf(mrun, tm);
        float sc = __expf(mrun - mnew);
        lp *= sc;
#pragma unroll
        for (int i = 0; i < 16; ++i) {
          oa0[i] *= sc;
          oa1[i] *= sc;
        }
        mrun = mnew;
      }

      // exp + per-lane partial row sum
      float pe0[16], pe1[16];
      float ls = 0.f;
#pragma unroll
      for (int r = 0; r < 16; ++r) {
        pe0[r] = __expf(s0[r] - mrun);
        ls += pe0[r];
      }
      if (!skip1) {
#pragma unroll
        for (int r = 0; r < 16; ++r) {
          pe1[r] = __expf(s1[r] - mrun);
          ls += pe1[r];
        }
      }
      lp += ls;

      // pack P into A-fragments: 4 cvt_pk + 2 permlane32_swap per k-step
      union {
        unsigned u[4];
        bf16x8 v;
      } pa[4];
#pragma unroll
      for (int ks2 = 0; ks2 < 2; ++ks2) {
        unsigned c0 = cvtpk_bf16(pe0[8 * ks2 + 0], pe0[8 * ks2 + 1]);
        unsigned c1 = cvtpk_bf16(pe0[8 * ks2 + 2], pe0[8 * ks2 + 3]);
        unsigned c2 = cvtpk_bf16(pe0[8 * ks2 + 4], pe0[8 * ks2 + 5]);
        unsigned c3 = cvtpk_bf16(pe0[8 * ks2 + 6], pe0[8 * ks2 + 7]);
        asm("v_permlane32_swap_b32 %0, %1" : "+v"(c0), "+v"(c2));
        asm("v_permlane32_swap_b32 %0, %1" : "+v"(c1), "+v"(c3));
        pa[ks2].u[0] = c0;
        pa[ks2].u[1] = c1;
        pa[ks2].u[2] = c2;
        pa[ks2].u[3] = c3;
      }
      if (!skip1) {
#pragma unroll
        for (int ks2 = 0; ks2 < 2; ++ks2) {
          unsigned c0 = cvtpk_bf16(pe1[8 * ks2 + 0], pe1[8 * ks2 + 1]);
          unsigned c1 = cvtpk_bf16(pe1[8 * ks2 + 2], pe1[8 * ks2 + 3]);
          unsigned c2 = cvtpk_bf16(pe1[8 * ks2 + 4], pe1[8 * ks2 + 5]);
          unsigned c3 = cvtpk_bf16(pe1[8 * ks2 + 6], pe1[8 * ks2 + 7]);
          asm("v_permlane32_swap_b32 %0, %1" : "+v"(c0), "+v"(c2));
          asm("v_permlane32_swap_b32 %0, %1" : "+v"(c1), "+v"(c3));
          pa[2 + ks2].u[0] = c0;
          pa[2 + ks2].u[1] = c1;
          pa[2 + ks2].u[2] = c2;
          pa[2 + ks2].u[3] = c3;
        }
      }

      // PV: O[q][d] += P·V
#pragma unroll
      for (int ks = 0; ks < 2; ++ks) {
        oa0 = __builtin_amdgcn_mfma_f32_32x32x16_bf16(pa[ks].v, vf0[ks], oa0, 0, 0, 0);
        oa1 = __builtin_amdgcn_mfma_f32_32x32x16_bf16(pa[ks].v, vf1[ks], oa1, 0, 0, 0);
      }
      if (!skip1) {
#pragma unroll
        for (int ks = 2; ks < 4; ++ks) {
          oa0 = __builtin_amdgcn_mfma_f32_32x32x16_bf16(pa[ks].v, vf0[ks], oa0, 0, 0, 0);
          oa1 = __builtin_amdgcn_mfma_f32_32x32x16_bf16(pa[ks].v, vf1[ks], oa1, 0, 0, 0);
        }
      }
    }

    // epilogue: row-sum finalize (one exchange), broadcast per output row, store
    float lt = lp + __shfl_xor(lp, 32);
#pragma unroll
    for (int r = 0; r < 16; ++r) {
      int cr = (r & 3) + 8 * (r >> 2) + 4 * hi;
      float lrow = __shfl(lt, cr);
      float inv = 1.0f / lrow;
      size_t base = ((size_t)bz * T_ + q0 + cr) * DIN + h * HD_;
      ctx[base + l31] = f2b(oa0[r] * inv);
      ctx[base + 32 + l31] = f2b(oa1[r] * inv);
    }
  }
}

extern "C" void kernel_launch(void* const* d_in, const int* in_sizes, int n_in,
                              void* d_out, int out_size, void* d_ws, size_t ws_size,
                              hipStream_t stream) {
  const float* x = (const float*)d_in[0];
  const float* cosp = (const float*)d_in[1];
  const float* sinp = (const float*)d_in[2];
  const float* wq = (const float*)d_in[3];
  const float* bq = (const float*)d_in[4];
  const float* wk = (const float*)d_in[5];
  const float* bk = (const float*)d_in[6];
  const float* wv = (const float*)d_in[7];
  const float* bv = (const float*)d_in[8];
  const float* wo = (const float*)d_in[9];
  const float* bo = (const float*)d_in[10];

  float* out = (float*)d_out;
  float* kout = out + (size_t)B_ * T_ * DIN;
  float* vout = kout + (size_t)B_ * KV_ * T_ * HD_;

  // Workspace layout with reuse (peak 60 MB):
  //   region A @ 0MB  (16MB): xb      -> qbuf  (xb dead after gemm1)
  //   region B @ 16MB (12MB): wqkv    -> kbuf+vbuf (wqkv dead after gemm1)
  //   region C @ 28MB ( 8MB): wob     (static)
  //   region D @ 36MB (24MB): cqkv bf16 -> ctxb(36..52) + vtb(52..56)
  char* ws = (char*)d_ws;
  unsigned short* xb   = (unsigned short*)(ws + 0);
  unsigned short* wqkv = (unsigned short*)(ws + (size_t)16 * 1024 * 1024);
  unsigned short* wob  = (unsigned short*)(ws + (size_t)28 * 1024 * 1024);
  unsigned short* cqkv = (unsigned short*)(ws + (size_t)36 * 1024 * 1024);

  unsigned short* qbuf = xb;
  unsigned short* kbuf = wqkv;
  unsigned short* vbuf = wqkv + (size_t)2097152;
  unsigned short* ctxb = cqkv;
  unsigned short* vtb  = (unsigned short*)(ws + (size_t)52 * 1024 * 1024);

  // f32 -> bf16 conversions
  cvt_bf16<<<8192, 256, 0, stream>>>(x, xb, 2097152);
  cvt_bf16<<<4096, 256, 0, stream>>>(wq, wqkv, 1048576);
  cvt_bf16<<<1024, 256, 0, stream>>>(wk, wqkv + (size_t)2048 * 2048, 262144);
  cvt_bf16<<<1024, 256, 0, stream>>>(wv, wqkv + (size_t)2048 * 2048 + (size_t)512 * 2048, 262144);
  cvt_bf16<<<4096, 256, 0, stream>>>(wo, wob, 1048576);

  // QKV projection: (4096 x 2048) @ (3072 x 2048)^T -> bf16 cqkv
  gemm_bt<<<dim3(24, 32), 256, 0, stream>>>(xb, wqkv, nullptr, cqkv, 4096, 3072, 2048, 1);

  // bias + RoPE + scatter
  rope_scatter<<<4096, 256, 0, stream>>>(cqkv, bq, bk, bv, cosp, sinp, qbuf, kbuf,
                                         vbuf, kout, vout);

  // V transpose: vbuf[t][d] -> vtb[d][t]
  transpose_v<<<dim3(T_ / 64, B_ * KV_), 256, 0, stream>>>(vbuf, vtb);

  // causal GQA flash attention (swapped-QK^T 32x32, paired q-tiles)
  attn<<<dim3(8, H_, B_), 256, 0, stream>>>(qbuf, kbuf, vtb, ctxb);

  // output projection: (4096 x 2048) @ (2048 x 2048)^T + bo -> f32 out
  gemm_bt<<<dim3(16, 32), 256, 0, stream>>>(ctxb, wob, bo, out, 4096, 2048, 2048, 0);
}

// Round 11
// 413.956 us; speedup vs baseline: 1.8436x; 1.0760x over previous
//
#include <hip/hip_runtime.h>
#include <cstdint>
#include <cstddef>

typedef short bf16x8 __attribute__((ext_vector_type(8)));
typedef float f32x4 __attribute__((ext_vector_type(4)));
typedef float f32x16 __attribute__((ext_vector_type(16)));

#define B_ 2
#define T_ 2048
#define DIN 2048
#define H_ 32
#define HD_ 64
#define KV_ 8

__device__ __forceinline__ unsigned short f2b(float f) {
  unsigned int u = __float_as_uint(f);
  u += 0x7fffu + ((u >> 16) & 1u);
  return (unsigned short)(u >> 16);
}

__device__ __forceinline__ float b2f(unsigned short b) {
  return __uint_as_float(((unsigned int)b) << 16);
}

__device__ __forceinline__ unsigned cvtpk_bf16(float lo, float hi) {
  unsigned r;
  asm("v_cvt_pk_bf16_f32 %0, %1, %2" : "=v"(r) : "v"(lo), "v"(hi));
  return r;
}

__device__ __forceinline__ void gload_lds16(const void* g, void* l) {
  __builtin_amdgcn_global_load_lds(
      (const unsigned int __attribute__((address_space(1)))*)g,
      (unsigned int __attribute__((address_space(3)))*)l, 16, 0, 0);
}

__global__ __launch_bounds__(256) void cvt_bf16(const float* __restrict__ in,
                                                unsigned short* __restrict__ out,
                                                int n4) {
  int i = blockIdx.x * 256 + threadIdx.x;
  if (i >= n4) return;
  float4 v = ((const float4*)in)[i];
  uint2 o;
  o.x = (unsigned)f2b(v.x) | ((unsigned)f2b(v.y) << 16);
  o.y = (unsigned)f2b(v.z) | ((unsigned)f2b(v.w) << 16);
  ((uint2*)out)[i] = o;
}

// C[M][N] = A[M][K] * Bw[N][K]^T (+bias). bf16 inputs; f32 or bf16 out.
__global__ __launch_bounds__(256) void gemm_bt(const unsigned short* __restrict__ A,
                                               const unsigned short* __restrict__ Bw,
                                               const float* __restrict__ bias,
                                               void* __restrict__ Cout,
                                               int M, int N, int K, int out_bf16) {
  __shared__ short As[128 * 64];
  __shared__ short Bs[128 * 64];
  const int tid = threadIdx.x;
  const int lane = tid & 63;
  const int wid = tid >> 6;
  const int wr = (wid >> 1) * 64;
  const int wc = (wid & 1) * 64;
  const int bm = blockIdx.y * 128;
  const int bn = blockIdx.x * 128;
  const int lr = lane & 15;
  const int lk = (lane >> 4) * 8;
  f32x4 acc[4][4] = {};

  for (int kt = 0; kt < K; kt += 64) {
    __syncthreads();
#pragma unroll
    for (int it = 0; it < 4; ++it) {
      int c = it * 256 + tid;
      int r = c >> 3;
      int c8 = (c & 7) * 8;
      gload_lds16(A + (size_t)(bm + r) * K + kt + c8, &As[c * 8]);
      gload_lds16(Bw + (size_t)(bn + r) * K + kt + c8, &Bs[c * 8]);
    }
    __syncthreads();
#pragma unroll
    for (int kk = 0; kk < 2; ++kk) {
      bf16x8 af[4], bfr[4];
#pragma unroll
      for (int m = 0; m < 4; ++m)
        af[m] = *(const bf16x8*)&As[(wr + m * 16 + lr) * 64 + kk * 32 + lk];
#pragma unroll
      for (int n = 0; n < 4; ++n)
        bfr[n] = *(const bf16x8*)&Bs[(wc + n * 16 + lr) * 64 + kk * 32 + lk];
#pragma unroll
      for (int m = 0; m < 4; ++m)
#pragma unroll
        for (int n = 0; n < 4; ++n)
          acc[m][n] = __builtin_amdgcn_mfma_f32_16x16x32_bf16(af[m], bfr[n], acc[m][n], 0, 0, 0);
    }
  }
  const int r0 = bm + wr + (lane >> 4) * 4;
  const int c0 = bn + wc + lr;
#pragma unroll
  for (int m = 0; m < 4; ++m)
#pragma unroll
    for (int n = 0; n < 4; ++n) {
      int col = c0 + n * 16;
      float bb = bias ? bias[col] : 0.0f;
#pragma unroll
      for (int r = 0; r < 4; ++r) {
        float val = acc[m][n][r] + bb;
        size_t idx = (size_t)(r0 + m * 16 + r) * N + col;
        if (out_bf16)
          ((unsigned short*)Cout)[idx] = f2b(val);
        else
          ((float*)Cout)[idx] = val;
      }
    }
}

// bias + RoPE + scatter into attention layouts; K/V also to f32 outputs.
__global__ __launch_bounds__(256) void rope_scatter(
    const unsigned short* __restrict__ cqkv, const float* __restrict__ bq,
    const float* __restrict__ bk, const float* __restrict__ bv,
    const float* __restrict__ cosp, const float* __restrict__ sinp,
    unsigned short* __restrict__ qbuf, unsigned short* __restrict__ kbuf,
    unsigned short* __restrict__ vbuf, float* __restrict__ kout,
    float* __restrict__ vout) {
  const int bt = blockIdx.x;
  const int b = bt >> 11;
  const int t = bt & 2047;
  const int tid = threadIdx.x;
  const unsigned short* row = cqkv + (size_t)bt * 3072;

  for (int p = tid; p < 1024; p += 256) {
    int h = p >> 5, i = p & 31;
    float c = cosp[t * 32 + i], s = sinp[t * 32 + i];
    float q0 = b2f(row[2 * p]) + bq[2 * p];
    float q1 = b2f(row[2 * p + 1]) + bq[2 * p + 1];
    float qe = (q0 * c - q1 * s) * 0.125f;
    float qo = (q0 * s + q1 * c) * 0.125f;
    size_t base = ((size_t)(b * H_ + h) * T_ + t) * HD_ + 2 * i;
    qbuf[base] = f2b(qe);
    qbuf[base + 1] = f2b(qo);
  }
  {
    int p = tid;
    if (p < 256) {
      int kvh = p >> 5, i = p & 31;
      float c = cosp[t * 32 + i], s = sinp[t * 32 + i];
      float k0 = b2f(row[2048 + 2 * p]) + bk[2 * p];
      float k1 = b2f(row[2048 + 2 * p + 1]) + bk[2 * p + 1];
      float ke = k0 * c - k1 * s;
      float ko = k0 * s + k1 * c;
      size_t base = ((size_t)(b * KV_ + kvh) * T_ + t) * HD_ + 2 * i;
      kout[base] = ke;
      kout[base + 1] = ko;
      kbuf[base] = f2b(ke);
      kbuf[base + 1] = f2b(ko);
    }
  }
  for (int j = tid; j < 512; j += 256) {
    int kvh = j >> 6, d = j & 63;
    float v = b2f(row[2560 + j]) + bv[j];
    size_t base = ((size_t)(b * KV_ + kvh) * T_ + t) * HD_ + d;
    vout[base] = v;
    vbuf[base] = f2b(v);
  }
}

// ---------------------------------------------------------------------------
// Pack K and V^T into MFMA-fragment order. Per-tile stride = 4096 elements
// (64 kv x 64 d). 512 chunks of 8 per tile (g in 0..15):
// kpack idx (per bkh): tile*4096 + ((half*8 + ds*2 + hi)*32 + l31)*8 + j
//   = K[tile*64 + half*32 + l31][ds*16 + hi*8 + j]
// vpack idx (per bkh): tile*4096 + ((dhalf*8 + ks*2 + hi)*32 + l31)*8 + j
//   = V[tile*64 + ks*16 + hi*8 + j][dhalf*32 + l31]
// grid(32 tiles, 16 bkh), 256 thr.
// ---------------------------------------------------------------------------
__global__ __launch_bounds__(256) void pack_kv(const unsigned short* __restrict__ kbuf,
                                               const unsigned short* __restrict__ vbuf,
                                               unsigned short* __restrict__ kpack,
                                               unsigned short* __restrict__ vpack) {
  __shared__ unsigned short vtile[64][72];
  const int tid = threadIdx.x;
  const int tile = blockIdx.x;
  const int bkh = blockIdx.y;
  const unsigned short* kb = kbuf + (size_t)bkh * T_ * HD_;
  const unsigned short* vb = vbuf + (size_t)bkh * T_ * HD_;
  unsigned short* kp = kpack + (size_t)bkh * T_ * HD_ + (size_t)tile * 4096;
  unsigned short* vp = vpack + (size_t)bkh * T_ * HD_ + (size_t)tile * 4096;

  // K: 512 fragment-ordered chunks (strided reads, coalesced writes)
#pragma unroll
  for (int it = 0; it < 2; ++it) {
    int c = it * 256 + tid;           // 0..511
    int g = c >> 5, l31 = c & 31;     // g 0..15
    int half = g >> 3, ds = (g >> 1) & 3, hi = g & 1;
    int row = tile * 64 + half * 32 + l31;
    int col = ds * 16 + hi * 8;
    bf16x8 v = *(const bf16x8*)(kb + (size_t)row * HD_ + col);
    *(bf16x8*)(kp + c * 8) = v;
  }
  // V: stage 64x64 tile into LDS, then gather transposed fragments
#pragma unroll
  for (int it = 0; it < 2; ++it) {
    int c = it * 256 + tid;
    int r = c >> 3, c8 = (c & 7) * 8;
    *(bf16x8*)&vtile[r][c8] = *(const bf16x8*)(vb + (size_t)(tile * 64 + r) * HD_ + c8);
  }
  __syncthreads();
#pragma unroll
  for (int it = 0; it < 2; ++it) {
    int c = it * 256 + tid;           // 0..511
    int g = c >> 5, l31 = c & 31;     // g 0..15
    int dhalf = g >> 3, ks = (g >> 1) & 3, hi = g & 1;
    int d = dhalf * 32 + l31;
    int t0 = ks * 16 + hi * 8;
    bf16x8 v;
#pragma unroll
    for (int j = 0; j < 8; ++j) v[j] = (short)vtile[t0 + j][d];
    *(bf16x8*)(vp + c * 8) = v;
  }
}

// ---------------------------------------------------------------------------
// Causal GQA flash attention, swapped-QK^T 32x32, qt-paired, packed K/V:
// every fragment load in the kv loop is a contiguous 1KB wave-read.
// grid(8, H, B), 256 thr = 4 waves; wave w handles pair j=bx*4+w: qt=63-j, j.
// ---------------------------------------------------------------------------
__global__ __launch_bounds__(256) void attn(const unsigned short* __restrict__ Q,
                                            const unsigned short* __restrict__ Kp,
                                            const unsigned short* __restrict__ Vp,
                                            unsigned short* __restrict__ ctx) {
  const int h = blockIdx.y, bz = blockIdx.z;
  const int kvh = h >> 2;
  const int tid = threadIdx.x, lane = tid & 63, w = tid >> 6;
  const int jidx = (int)blockIdx.x * 4 + w;  // 0..31
  const int l31 = lane & 31, hi = lane >> 5;
  const float NEGINF = -__builtin_inff();

  const unsigned short* kpb = Kp + (size_t)(bz * KV_ + kvh) * T_ * HD_;
  const unsigned short* vpb = Vp + (size_t)(bz * KV_ + kvh) * T_ * HD_;

  for (int p2 = 0; p2 < 2; ++p2) {
    const int qt = p2 ? jidx : (63 - jidx);  // heavy tile first
    const int q0 = qt * 32;

    const unsigned short* qb = Q + ((size_t)(bz * H_ + h) * T_ + q0) * HD_;

    // Q fragments (B-operand: col=q=l31, k=d)
    bf16x8 qf[4];
#pragma unroll
    for (int ds = 0; ds < 4; ++ds)
      qf[ds] = *(const bf16x8*)(qb + (size_t)l31 * HD_ + ds * 16 + hi * 8);

    float mrun = NEGINF, lp = 0.f;
    f32x16 oa0 = {}, oa1 = {};
    const int niter = (qt >> 1) + 1;
    const bool evenq = (qt & 1) == 0;

    for (int it = 0; it < niter; ++it) {
      const bool last = (it == niter - 1);
      const bool skip1 = last && evenq;  // upper 32-kv half fully masked
      const unsigned short* kp = kpb + (size_t)it * 4096;
      const unsigned short* vp = vpb + (size_t)it * 4096;
      const int fo = hi * 256 + l31 * 8;  // per-lane fragment offset

      // K fragments (A-operand: row=kv, k=d) — contiguous wave-reads
      bf16x8 kf0[4], kf1[4];
#pragma unroll
      for (int ds = 0; ds < 4; ++ds)
        kf0[ds] = *(const bf16x8*)(kp + ds * 512 + fo);
      if (!skip1) {
#pragma unroll
        for (int ds = 0; ds < 4; ++ds)
          kf1[ds] = *(const bf16x8*)(kp + 2048 + ds * 512 + fo);
      }
      // V fragments (B-operand for PV: col=d, k=kv)
      bf16x8 vf0[4], vf1[4];
#pragma unroll
      for (int ks = 0; ks < 2; ++ks) {
        vf0[ks] = *(const bf16x8*)(vp + ks * 512 + fo);
        vf1[ks] = *(const bf16x8*)(vp + 2048 + ks * 512 + fo);
      }
      if (!skip1) {
#pragma unroll
        for (int ks = 2; ks < 4; ++ks) {
          vf0[ks] = *(const bf16x8*)(vp + ks * 512 + fo);
          vf1[ks] = *(const bf16x8*)(vp + 2048 + ks * 512 + fo);
        }
      }

      // S^T tiles: D[kv][q] = K·Q^T
      f32x16 s0 = {}, s1 = {};
#pragma unroll
      for (int ds = 0; ds < 4; ++ds)
        s0 = __builtin_amdgcn_mfma_f32_32x32x16_bf16(kf0[ds], qf[ds], s0, 0, 0, 0);
      if (!skip1) {
#pragma unroll
        for (int ds = 0; ds < 4; ++ds)
          s1 = __builtin_amdgcn_mfma_f32_32x32x16_bf16(kf1[ds], qf[ds], s1, 0, 0, 0);
      }

      // causal mask on the diagonal 32-kv half (local cond: crow > q-col)
      if (last) {
#pragma unroll
        for (int r = 0; r < 16; ++r) {
          int cr = (r & 3) + 8 * (r >> 2) + 4 * hi;
          if (evenq)
            s0[r] = (cr > l31) ? NEGINF : s0[r];
          else
            s1[r] = (cr > l31) ? NEGINF : s1[r];
        }
      }

      // row max: in-lane tree + one cross-half exchange
      float a = fmaxf(fmaxf(s0[0], s0[1]), fmaxf(s0[2], s0[3]));
      float b = fmaxf(fmaxf(s0[4], s0[5]), fmaxf(s0[6], s0[7]));
      float c = fmaxf(fmaxf(s0[8], s0[9]), fmaxf(s0[10], s0[11]));
      float d = fmaxf(fmaxf(s0[12], s0[13]), fmaxf(s0[14], s0[15]));
      float tm = fmaxf(fmaxf(a, b), fmaxf(c, d));
      if (!skip1) {
        float a1 = fmaxf(fmaxf(s1[0], s1[1]), fmaxf(s1[2], s1[3]));
        float b1 = fmaxf(fmaxf(s1[4], s1[5]), fmaxf(s1[6], s1[7]));
        float c1 = fmaxf(fmaxf(s1[8], s1[9]), fmaxf(s1[10], s1[11]));
        float d1 = fmaxf(fmaxf(s1[12], s1[13]), fmaxf(s1[14], s1[15]));
        tm = fmaxf(tm, fmaxf(fmaxf(a1, b1), fmaxf(c1, d1)));
      }
      tm = fmaxf(tm, __shfl_xor(tm, 32));

      // defer-max (THR=8)
      if (!__all(tm - mrun <= 8.0f)) {
        float mnew = fmaxf(mrun, tm);
        float sc = __expf(mrun - mnew);
        lp *= sc;
#pragma unroll
        for (int i = 0; i < 16; ++i) {
          oa0[i] *= sc;
          oa1[i] *= sc;
        }
        mrun = mnew;
      }

      // exp + per-lane partial row sum
      float pe0[16], pe1[16];
      float ls = 0.f;
#pragma unroll
      for (int r = 0; r < 16; ++r) {
        pe0[r] = __expf(s0[r] - mrun);
        ls += pe0[r];
      }
      if (!skip1) {
#pragma unroll
        for (int r = 0; r < 16; ++r) {
          pe1[r] = __expf(s1[r] - mrun);
          ls += pe1[r];
        }
      }
      lp += ls;

      // pack P into A-fragments: 4 cvt_pk + 2 permlane32_swap per k-step
      union {
        unsigned u[4];
        bf16x8 v;
      } pa[4];
#pragma unroll
      for (int ks2 = 0; ks2 < 2; ++ks2) {
        unsigned c0 = cvtpk_bf16(pe0[8 * ks2 + 0], pe0[8 * ks2 + 1]);
        unsigned c1 = cvtpk_bf16(pe0[8 * ks2 + 2], pe0[8 * ks2 + 3]);
        unsigned c2 = cvtpk_bf16(pe0[8 * ks2 + 4], pe0[8 * ks2 + 5]);
        unsigned c3 = cvtpk_bf16(pe0[8 * ks2 + 6], pe0[8 * ks2 + 7]);
        asm("v_permlane32_swap_b32 %0, %1" : "+v"(c0), "+v"(c2));
        asm("v_permlane32_swap_b32 %0, %1" : "+v"(c1), "+v"(c3));
        pa[ks2].u[0] = c0;
        pa[ks2].u[1] = c1;
        pa[ks2].u[2] = c2;
        pa[ks2].u[3] = c3;
      }
      if (!skip1) {
#pragma unroll
        for (int ks2 = 0; ks2 < 2; ++ks2) {
          unsigned c0 = cvtpk_bf16(pe1[8 * ks2 + 0], pe1[8 * ks2 + 1]);
          unsigned c1 = cvtpk_bf16(pe1[8 * ks2 + 2], pe1[8 * ks2 + 3]);
          unsigned c2 = cvtpk_bf16(pe1[8 * ks2 + 4], pe1[8 * ks2 + 5]);
          unsigned c3 = cvtpk_bf16(pe1[8 * ks2 + 6], pe1[8 * ks2 + 7]);
          asm("v_permlane32_swap_b32 %0, %1" : "+v"(c0), "+v"(c2));
          asm("v_permlane32_swap_b32 %0, %1" : "+v"(c1), "+v"(c3));
          pa[2 + ks2].u[0] = c0;
          pa[2 + ks2].u[1] = c1;
          pa[2 + ks2].u[2] = c2;
          pa[2 + ks2].u[3] = c3;
        }
      }

      // PV: O[q][d] += P·V
#pragma unroll
      for (int ks = 0; ks < 2; ++ks) {
        oa0 = __builtin_amdgcn_mfma_f32_32x32x16_bf16(pa[ks].v, vf0[ks], oa0, 0, 0, 0);
        oa1 = __builtin_amdgcn_mfma_f32_32x32x16_bf16(pa[ks].v, vf1[ks], oa1, 0, 0, 0);
      }
      if (!skip1) {
#pragma unroll
        for (int ks = 2; ks < 4; ++ks) {
          oa0 = __builtin_amdgcn_mfma_f32_32x32x16_bf16(pa[ks].v, vf0[ks], oa0, 0, 0, 0);
          oa1 = __builtin_amdgcn_mfma_f32_32x32x16_bf16(pa[ks].v, vf1[ks], oa1, 0, 0, 0);
        }
      }
    }

    // epilogue: row-sum finalize, broadcast per output row, store
    float lt = lp + __shfl_xor(lp, 32);
#pragma unroll
    for (int r = 0; r < 16; ++r) {
      int cr = (r & 3) + 8 * (r >> 2) + 4 * hi;
      float lrow = __shfl(lt, cr);
      float inv = 1.0f / lrow;
      size_t base = ((size_t)bz * T_ + q0 + cr) * DIN + h * HD_;
      ctx[base + l31] = f2b(oa0[r] * inv);
      ctx[base + 32 + l31] = f2b(oa1[r] * inv);
    }
  }
}

extern "C" void kernel_launch(void* const* d_in, const int* in_sizes, int n_in,
                              void* d_out, int out_size, void* d_ws, size_t ws_size,
                              hipStream_t stream) {
  const float* x = (const float*)d_in[0];
  const float* cosp = (const float*)d_in[1];
  const float* sinp = (const float*)d_in[2];
  const float* wq = (const float*)d_in[3];
  const float* bq = (const float*)d_in[4];
  const float* wk = (const float*)d_in[5];
  const float* bk = (const float*)d_in[6];
  const float* wv = (const float*)d_in[7];
  const float* bv = (const float*)d_in[8];
  const float* wo = (const float*)d_in[9];
  const float* bo = (const float*)d_in[10];

  float* out = (float*)d_out;
  float* kout = out + (size_t)B_ * T_ * DIN;
  float* vout = kout + (size_t)B_ * KV_ * T_ * HD_;

  // Flat workspace layout (peak 116 MB; round-2 ran with 120 MB).
  const size_t MB = 1024 * 1024;
  char* ws = (char*)d_ws;
  unsigned short* xb    = (unsigned short*)(ws + 0 * MB);     // 16MB
  unsigned short* wqkv  = (unsigned short*)(ws + 16 * MB);    // 12MB
  unsigned short* wob   = (unsigned short*)(ws + 28 * MB);    // 8MB
  unsigned short* cqkv  = (unsigned short*)(ws + 36 * MB);    // 24MB
  unsigned short* qbuf  = (unsigned short*)(ws + 60 * MB);    // 16MB
  unsigned short* kbuf  = (unsigned short*)(ws + 76 * MB);    // 4MB
  unsigned short* vbuf  = (unsigned short*)(ws + 80 * MB);    // 4MB
  unsigned short* kpack = (unsigned short*)(ws + 84 * MB);    // 4MB (+4 pad)
  unsigned short* vpack = (unsigned short*)(ws + 92 * MB);    // 4MB (+4 pad)
  unsigned short* ctxb  = (unsigned short*)(ws + 100 * MB);   // 16MB

  // f32 -> bf16 conversions
  cvt_bf16<<<8192, 256, 0, stream>>>(x, xb, 2097152);
  cvt_bf16<<<4096, 256, 0, stream>>>(wq, wqkv, 1048576);
  cvt_bf16<<<1024, 256, 0, stream>>>(wk, wqkv + (size_t)2048 * 2048, 262144);
  cvt_bf16<<<1024, 256, 0, stream>>>(wv, wqkv + (size_t)2048 * 2048 + (size_t)512 * 2048, 262144);
  cvt_bf16<<<4096, 256, 0, stream>>>(wo, wob, 1048576);

  // QKV projection: (4096 x 2048) @ (3072 x 2048)^T -> bf16 cqkv
  gemm_bt<<<dim3(24, 32), 256, 0, stream>>>(xb, wqkv, nullptr, cqkv, 4096, 3072, 2048, 1);

  // bias + RoPE + scatter
  rope_scatter<<<4096, 256, 0, stream>>>(cqkv, bq, bk, bv, cosp, sinp, qbuf, kbuf,
                                         vbuf, kout, vout);

  // pack K/V into MFMA-fragment order (per-tile stride 4096)
  pack_kv<<<dim3(32, 16), 256, 0, stream>>>(kbuf, vbuf, kpack, vpack);

  // causal GQA flash attention (swapped-QK^T 32x32, paired, packed K/V)
  attn<<<dim3(8, H_, B_), 256, 0, stream>>>(qbuf, kpack, vpack, ctxb);

  // output projection: (4096 x 2048) @ (2048 x 2048)^T + bo -> f32 out
  gemm_bt<<<dim3(16, 32), 256, 0, stream>>>(ctxb, wob, bo, out, 4096, 2048, 2048, 0);
}